// Round 9
// baseline (4829.743 us; speedup 1.0000x reference)
//
#include <hip/hip_runtime.h>

using u8 = unsigned char;

// ---------------- mask init: m = (maskraw == 0) ----------------
__global__ void mask_init_k(const int* __restrict__ mr, u8* __restrict__ m, int N) {
    int i = blockIdx.x * blockDim.x + threadIdx.x;
    if (i < N) m[i] = (mr[i] == 0) ? 1 : 0;
}

// ---------------- mask pool 2x2x2 (logical OR), full batch ----------------
template <int SO>
__global__ void pool_k(const u8* __restrict__ mi, u8* __restrict__ mo) {
    const int N = 128 * SO * SO * SO;
    constexpr int SI = 2 * SO;
    int v = blockIdx.x * blockDim.x + threadIdx.x;
    if (v >= N) return;
    int t = v;
    int x = t % SO; t /= SO;
    int y = t % SO; t /= SO;
    int z = t % SO;
    int n = t / SO;
    u8 m = 0;
    for (int kd = 0; kd < 2; kd++)
        for (int kh = 0; kh < 2; kh++)
            for (int kw = 0; kw < 2; kw++)
                m |= mi[((n * SI + 2 * z + kd) * SI + 2 * y + kh) * SI + 2 * x + kw];
    mo[v] = m;
}

// ---------------- fused prepare conv (1->4, k=3) + BN stats reduce, full batch ----------------
__global__ void prep_reduce_k(const float* __restrict__ vox, const u8* __restrict__ m,
                              const float* __restrict__ wp, double* __restrict__ stats) {
    const int N = 128 * 32768;
    double cnt = 0.0, sx[4] = {0, 0, 0, 0}, s2[4] = {0, 0, 0, 0};
    int stride = gridDim.x * blockDim.x;
    for (int v = blockIdx.x * blockDim.x + threadIdx.x; v < N; v += stride) {
        if (!m[v]) continue;
        int t = v;
        int x = t & 31; t >>= 5;
        int y = t & 31; t >>= 5;
        int z = t & 31;
        int n = t >> 5;
        double p[4] = {0, 0, 0, 0};
        for (int kd = 0; kd < 3; kd++) {
            int zz = z + kd - 1; if ((unsigned)zz >= 32u) continue;
            for (int kh = 0; kh < 3; kh++) {
                int yy = y + kh - 1; if ((unsigned)yy >= 32u) continue;
                for (int kw = 0; kw < 3; kw++) {
                    int xx = x + kw - 1; if ((unsigned)xx >= 32u) continue;
                    int sv = ((n * 32 + zz) * 32 + yy) * 32 + xx;
                    if (!m[sv]) continue;
                    double xv = (double)vox[sv];
                    const float* w = wp + ((kd * 3 + kh) * 3 + kw) * 4;
#pragma unroll
                    for (int co = 0; co < 4; co++) p[co] += xv * (double)w[co];
                }
            }
        }
        cnt += 1.0;
#pragma unroll
        for (int c = 0; c < 4; c++) { sx[c] += p[c]; s2[c] += p[c] * p[c]; }
    }
#pragma unroll
    for (int off = 32; off > 0; off >>= 1) {
        cnt += __shfl_down(cnt, off, 64);
#pragma unroll
        for (int c = 0; c < 4; c++) {
            sx[c] += __shfl_down(sx[c], off, 64);
            s2[c] += __shfl_down(s2[c], off, 64);
        }
    }
    if ((threadIdx.x & 63) == 0) {
        atomicAdd(&stats[0], cnt);
#pragma unroll
        for (int c = 0; c < 4; c++) {
            atomicAdd(&stats[1 + c], sx[c]);
            atomicAdd(&stats[1 + 4 + c], s2[c]);
        }
    }
}

// ---------------- fused prepare conv + BN apply+ReLU, chunk of 32 samples ----------------
__global__ void prep_bn_k(const float* __restrict__ vox, const u8* __restrict__ m,
                          const float* __restrict__ wp, const double* __restrict__ params,
                          double* __restrict__ out) {
    const int N = 32 * 32768;
    int v = blockIdx.x * blockDim.x + threadIdx.x;
    if (v >= N) return;
    if (!m[v]) {
#pragma unroll
        for (int co = 0; co < 4; co++) out[(size_t)v * 4 + co] = 0.0;
        return;
    }
    int t = v;
    int x = t & 31; t >>= 5;
    int y = t & 31; t >>= 5;
    int z = t & 31;
    int n = t >> 5;
    double p[4] = {0, 0, 0, 0};
    for (int kd = 0; kd < 3; kd++) {
        int zz = z + kd - 1; if ((unsigned)zz >= 32u) continue;
        for (int kh = 0; kh < 3; kh++) {
            int yy = y + kh - 1; if ((unsigned)yy >= 32u) continue;
            for (int kw = 0; kw < 3; kw++) {
                int xx = x + kw - 1; if ((unsigned)xx >= 32u) continue;
                int sv = ((n * 32 + zz) * 32 + yy) * 32 + xx;
                if (!m[sv]) continue;
                double xv = (double)vox[sv];
                const float* w = wp + ((kd * 3 + kh) * 3 + kw) * 4;
#pragma unroll
                for (int co = 0; co < 4; co++) p[co] += xv * (double)w[co];
            }
        }
    }
#pragma unroll
    for (int co = 0; co < 4; co++)
        out[(size_t)v * 4 + co] = fmax(p[co] * params[co] + params[4 + co], 0.0);
}

// ---------------- plain conv (input pre-masked/zeroed), k=3 pad(1,1) or k=4 pad(1,2) ----------------
template <int K, int CIN, int COUT, int S, int NB>
__global__ void conv_k(const double* __restrict__ in, const float* __restrict__ w,
                       const u8* __restrict__ outmask, double* __restrict__ out) {
    const int N = NB * S * S * S;
    int v = blockIdx.x * blockDim.x + threadIdx.x;
    if (v >= N) return;
    if (!outmask[v]) {
#pragma unroll
        for (int co = 0; co < COUT; co++) out[(size_t)v * COUT + co] = 0.0;
        return;
    }
    int t = v;
    int x = t % S; t /= S;
    int y = t % S; t /= S;
    int z = t % S;
    int n = t / S;
    double acc[COUT];
#pragma unroll
    for (int co = 0; co < COUT; co++) acc[co] = 0.0;
    constexpr int PLO = (K - 1) / 2;
    for (int kd = 0; kd < K; kd++) {
        int zz = z + kd - PLO; if ((unsigned)zz >= (unsigned)S) continue;
        for (int kh = 0; kh < K; kh++) {
            int yy = y + kh - PLO; if ((unsigned)yy >= (unsigned)S) continue;
            for (int kw = 0; kw < K; kw++) {
                int xx = x + kw - PLO; if ((unsigned)xx >= (unsigned)S) continue;
                int sv = ((n * S + zz) * S + yy) * S + xx;
                const double* ip = in + (size_t)sv * CIN;
                const float* wpk = w + ((kd * K + kh) * K + kw) * CIN * COUT;
#pragma unroll
                for (int ci = 0; ci < CIN; ci++) {
                    double xv = ip[ci];
                    if (xv == 0.0) continue;
#pragma unroll
                    for (int co = 0; co < COUT; co++) acc[co] += xv * (double)wpk[ci * COUT + co];
                }
            }
        }
    }
#pragma unroll
    for (int co = 0; co < COUT; co++) out[(size_t)v * COUT + co] = acc[co];
}

// ---------------- conv k=3 with BN(affine+ReLU+mask) applied to input on load, full batch ----------------
template <int CIN, int COUT, int S>
__global__ void convbn_k(const double* __restrict__ in, const float* __restrict__ w,
                         const u8* __restrict__ mask, const double* __restrict__ params,
                         double* __restrict__ out) {
    const int N = 128 * S * S * S;
    int v = blockIdx.x * blockDim.x + threadIdx.x;
    if (v >= N) return;
    if (!mask[v]) {
#pragma unroll
        for (int co = 0; co < COUT; co++) out[(size_t)v * COUT + co] = 0.0;
        return;
    }
    int t = v;
    int x = t % S; t /= S;
    int y = t % S; t /= S;
    int z = t % S;
    int n = t / S;
    double acc[COUT];
#pragma unroll
    for (int co = 0; co < COUT; co++) acc[co] = 0.0;
    for (int kd = 0; kd < 3; kd++) {
        int zz = z + kd - 1; if ((unsigned)zz >= (unsigned)S) continue;
        for (int kh = 0; kh < 3; kh++) {
            int yy = y + kh - 1; if ((unsigned)yy >= (unsigned)S) continue;
            for (int kw = 0; kw < 3; kw++) {
                int xx = x + kw - 1; if ((unsigned)xx >= (unsigned)S) continue;
                int sv = ((n * S + zz) * S + yy) * S + xx;
                if (!mask[sv]) continue;
                const double* ip = in + (size_t)sv * CIN;
                const float* wpk = w + ((kd * 3 + kh) * 3 + kw) * CIN * COUT;
#pragma unroll
                for (int ci = 0; ci < CIN; ci++) {
                    double yv = fmax(ip[ci] * params[ci] + params[CIN + ci], 0.0);
                    if (yv == 0.0) continue;
#pragma unroll
                    for (int co = 0; co < COUT; co++) acc[co] += yv * (double)wpk[ci * COUT + co];
                }
            }
        }
    }
#pragma unroll
    for (int co = 0; co < COUT; co++) out[(size_t)v * COUT + co] = acc[co];
}

// ---------------- conv k=3 + fused sparsify; gate = parent (half-res) mask; writes new mask ----------------
// Gate: active iff acc0 > -delta * sum|terms|. delta=0 -> exact reference rule.
template <int CIN, int COUT, int S, int NB>
__global__ void conv3s_k(const double* __restrict__ in, const float* __restrict__ w,
                         const u8* __restrict__ pmask, u8* __restrict__ nmask,
                         double* __restrict__ out, double delta) {
    const int N = NB * S * S * S;
    constexpr int SP = S / 2;
    int v = blockIdx.x * blockDim.x + threadIdx.x;
    if (v >= N) return;
    int t = v;
    int x = t % S; t /= S;
    int y = t % S; t /= S;
    int z = t % S;
    int n = t / S;
    int pidx = ((n * SP + (z >> 1)) * SP + (y >> 1)) * SP + (x >> 1);
    if (!pmask[pidx]) {
        nmask[v] = 0;
#pragma unroll
        for (int co = 0; co < COUT; co++) out[(size_t)v * COUT + co] = 0.0;
        return;
    }
    double acc[COUT];
#pragma unroll
    for (int co = 0; co < COUT; co++) acc[co] = 0.0;
    double asum = 0.0;  // sum of |terms| for channel 0 (noise-band scale)
    for (int kd = 0; kd < 3; kd++) {
        int zz = z + kd - 1; if ((unsigned)zz >= (unsigned)S) continue;
        for (int kh = 0; kh < 3; kh++) {
            int yy = y + kh - 1; if ((unsigned)yy >= (unsigned)S) continue;
            for (int kw = 0; kw < 3; kw++) {
                int xx = x + kw - 1; if ((unsigned)xx >= (unsigned)S) continue;
                int sv = ((n * S + zz) * S + yy) * S + xx;
                const double* ip = in + (size_t)sv * CIN;
                const float* wpk = w + ((kd * 3 + kh) * 3 + kw) * CIN * COUT;
#pragma unroll
                for (int ci = 0; ci < CIN; ci++) {
                    double xv = ip[ci];
                    if (xv == 0.0) continue;
                    asum += fabs(xv * (double)wpk[ci * COUT + 0]);
#pragma unroll
                    for (int co = 0; co < COUT; co++) acc[co] += xv * (double)wpk[ci * COUT + co];
                }
            }
        }
    }
    u8 nm = (acc[0] > -delta * asum) ? 1 : 0;
    nmask[v] = nm;
#pragma unroll
    for (int co = 0; co < COUT; co++) out[(size_t)v * COUT + co] = nm ? acc[co] : 0.0;
}

// ---------------- strided down conv k=2 s=2 (input pre-masked) ----------------
template <int CIN, int COUT, int SO, int NB>
__global__ void down_k(const double* __restrict__ in, const float* __restrict__ w,
                       const u8* __restrict__ outmask, double* __restrict__ out) {
    const int N = NB * SO * SO * SO;
    constexpr int SI = 2 * SO;
    int v = blockIdx.x * blockDim.x + threadIdx.x;
    if (v >= N) return;
    if (!outmask[v]) {
#pragma unroll
        for (int co = 0; co < COUT; co++) out[(size_t)v * COUT + co] = 0.0;
        return;
    }
    int t = v;
    int x = t % SO; t /= SO;
    int y = t % SO; t /= SO;
    int z = t % SO;
    int n = t / SO;
    double acc[COUT];
#pragma unroll
    for (int co = 0; co < COUT; co++) acc[co] = 0.0;
    for (int kd = 0; kd < 2; kd++)
        for (int kh = 0; kh < 2; kh++)
            for (int kw = 0; kw < 2; kw++) {
                int sv = ((n * SI + 2 * z + kd) * SI + 2 * y + kh) * SI + 2 * x + kw;
                const double* ip = in + (size_t)sv * CIN;
                const float* wpk = w + ((kd * 2 + kh) * 2 + kw) * CIN * COUT;
#pragma unroll
                for (int ci = 0; ci < CIN; ci++) {
                    double xv = ip[ci];
                    if (xv == 0.0) continue;
#pragma unroll
                    for (int co = 0; co < COUT; co++) acc[co] += xv * (double)wpk[ci * COUT + co];
                }
            }
#pragma unroll
    for (int co = 0; co < COUT; co++) out[(size_t)v * COUT + co] = acc[co];
}

// ---------------- fused BN + transposed conv k=2 s=2: out[2j+r] = relu(aff(x[j]))*w[1-r] ----------------
template <int CIN, int COUT, int SI, int NB>
__global__ void upbn_k(const double* __restrict__ in, const float* __restrict__ w,
                       const u8* __restrict__ inmask, const double* __restrict__ params,
                       double* __restrict__ out) {
    constexpr int SO = 2 * SI;
    const int N = NB * SO * SO * SO;
    int v = blockIdx.x * blockDim.x + threadIdx.x;
    if (v >= N) return;
    int t = v;
    int x = t % SO; t /= SO;
    int y = t % SO; t /= SO;
    int z = t % SO;
    int n = t / SO;
    int sv = ((n * SI + (z >> 1)) * SI + (y >> 1)) * SI + (x >> 1);
    if (!inmask[sv]) {
#pragma unroll
        for (int co = 0; co < COUT; co++) out[(size_t)v * COUT + co] = 0.0;
        return;
    }
    int tap = ((1 - (z & 1)) * 2 + (1 - (y & 1))) * 2 + (1 - (x & 1));
    const float* wpk = w + tap * CIN * COUT;
    const double* ip = in + (size_t)sv * CIN;
    double acc[COUT];
#pragma unroll
    for (int co = 0; co < COUT; co++) acc[co] = 0.0;
#pragma unroll
    for (int ci = 0; ci < CIN; ci++) {
        double yv = fmax(ip[ci] * params[ci] + params[CIN + ci], 0.0);
        if (yv == 0.0) continue;
#pragma unroll
        for (int co = 0; co < COUT; co++) acc[co] += yv * (double)wpk[ci * COUT + co];
    }
#pragma unroll
    for (int co = 0; co < COUT; co++) out[(size_t)v * COUT + co] = acc[co];
}

// ---------------- BN masked reduce (plain input), fp64 ----------------
template <int C>
__global__ void bn_reduce_k(const double* __restrict__ x, const u8* __restrict__ m, int N,
                            double* __restrict__ stats) {
    double cnt = 0.0, sx[C], s2[C];
#pragma unroll
    for (int c = 0; c < C; c++) { sx[c] = 0.0; s2[c] = 0.0; }
    int stride = gridDim.x * blockDim.x;
    for (int v = blockIdx.x * blockDim.x + threadIdx.x; v < N; v += stride) {
        if (!m[v]) continue;
        cnt += 1.0;
#pragma unroll
        for (int c = 0; c < C; c++) {
            double xv = x[(size_t)v * C + c];
            sx[c] += xv;
            s2[c] += xv * xv;
        }
    }
#pragma unroll
    for (int off = 32; off > 0; off >>= 1) {
        cnt += __shfl_down(cnt, off, 64);
#pragma unroll
        for (int c = 0; c < C; c++) {
            sx[c] += __shfl_down(sx[c], off, 64);
            s2[c] += __shfl_down(s2[c], off, 64);
        }
    }
    if ((threadIdx.x & 63) == 0) {
        atomicAdd(&stats[0], cnt);
#pragma unroll
        for (int c = 0; c < C; c++) {
            atomicAdd(&stats[1 + c], sx[c]);
            atomicAdd(&stats[1 + C + c], s2[c]);
        }
    }
}

// ---------------- BN finalize ----------------
template <int C>
__global__ void bn_final_k(const double* __restrict__ stats, const float* __restrict__ g,
                           const float* __restrict__ b, double* __restrict__ params) {
    int c = threadIdx.x;
    if (c >= C) return;
    double cnt = stats[0];
    if (cnt < 1.0) cnt = 1.0;
    double mean = stats[1 + c] / cnt;
    double var = stats[1 + C + c] / cnt - mean * mean;
    double sc = (double)g[c] / sqrt(var + 1e-4);
    params[c] = sc;
    params[C + c] = (double)b[c] - mean * sc;
}

// ---------------- final output conv k=3, 4->1, chunk of 32 samples, fp32 out ----------------
__global__ void outconv_k(const double* __restrict__ in, const float* __restrict__ w,
                          const u8* __restrict__ mask, float* __restrict__ out) {
    const int N = 32 * 32768;
    int v = blockIdx.x * blockDim.x + threadIdx.x;
    if (v >= N) return;
    if (!mask[v]) { out[v] = 0.f; return; }
    int t = v;
    int x = t & 31; t >>= 5;
    int y = t & 31; t >>= 5;
    int z = t & 31;
    int n = t >> 5;
    double acc = 0.0;
    for (int kd = 0; kd < 3; kd++) {
        int zz = z + kd - 1; if ((unsigned)zz >= 32u) continue;
        for (int kh = 0; kh < 3; kh++) {
            int yy = y + kh - 1; if ((unsigned)yy >= 32u) continue;
            for (int kw = 0; kw < 3; kw++) {
                int xx = x + kw - 1; if ((unsigned)xx >= 32u) continue;
                int sv = ((n * 32 + zz) * 32 + yy) * 32 + xx;
                const double* ip = in + (size_t)sv * 4;
                const float* wpk = w + ((kd * 3 + kh) * 3 + kw) * 4;
#pragma unroll
                for (int ci = 0; ci < 4; ci++) acc += ip[ci] * (double)wpk[ci];
            }
        }
    }
    out[v] = (float)acc;
}

// ---------------- hidden: NDHWC (4^3, 32ch) -> NCDHW flat, f32 out ----------------
__global__ void hidden_k(const double* __restrict__ x, float* __restrict__ out) {
    int i = blockIdx.x * blockDim.x + threadIdx.x;
    if (i >= 128 * 2048) return;
    int b = i >> 11;
    int r = i & 2047;
    int c = r >> 6;
    int s = r & 63;
    int d = s >> 4;
    int h = (s >> 2) & 3;
    int w = s & 3;
    out[i] = (float)x[((((b * 4 + d) * 4 + h) * 4 + w) << 5) + c];
}

extern "C" void kernel_launch(void* const* d_in, const int* in_sizes, int n_in,
                              void* d_out, int out_size, void* d_ws, size_t ws_size,
                              hipStream_t stream) {
    const float* vox = (const float*)d_in[0];
    const int* mraw = (const int*)d_in[1];
    const float* wp = (const float*)d_in[2];
    const float* g_e0 = (const float*)d_in[3];
    const float* b_e0 = (const float*)d_in[4];
    const float* ws_e0 = (const float*)d_in[5];
    const float* wd_e0 = (const float*)d_in[6];
    const float* g_e1 = (const float*)d_in[7];
    const float* b_e1 = (const float*)d_in[8];
    const float* ws_e1 = (const float*)d_in[9];
    const float* wd_e1 = (const float*)d_in[10];
    const float* g_e2 = (const float*)d_in[11];
    const float* b_e2 = (const float*)d_in[12];
    const float* ws_e2 = (const float*)d_in[13];
    const float* wd_e2 = (const float*)d_in[14];
    const float* g_d0 = (const float*)d_in[15];
    const float* b_d0 = (const float*)d_in[16];
    const float* wu_d0 = (const float*)d_in[17];
    const float* ws3_d0 = (const float*)d_in[18];
    const float* ws4_d0 = (const float*)d_in[19];
    const float* g_d1 = (const float*)d_in[20];
    const float* b_d1 = (const float*)d_in[21];
    const float* wu_d1 = (const float*)d_in[22];
    const float* ws3_d1 = (const float*)d_in[23];
    const float* ws4_d1 = (const float*)d_in[24];
    const float* g_d2 = (const float*)d_in[25];
    const float* b_d2 = (const float*)d_in[26];
    const float* wu_d2 = (const float*)d_in[27];
    const float* ws3_d2 = (const float*)d_in[28];
    const float* ws4_d2 = (const float*)d_in[29];
    const float* wo = (const float*)d_in[30];
    float* out = (float*)d_out;

    // ---- workspace: doubles first, then u8 masks (~162 MB total) ----
    double* wsd = (double*)d_ws;
    size_t offd = 0;
    auto allocd = [&](size_t n) { double* p = wsd + offd; offd += n; return p; };
    double* P = allocd(4194304);   // 128*16^3*8ch
    double* Q = allocd(4194304);
    double* A = allocd(4194304);   // chunk: 32*32^3*4ch
    double* B = allocd(4194304);
    double* U = allocd(1048576);   // 128*8^3*16ch
    double* V = allocd(1048576);
    double* T = allocd(262144);    // 128*4^3*32ch
    double* stats = allocd(128);
    double* params = allocd(128);
    u8* wsm = (u8*)(wsd + offd);
    size_t offm = 0;
    auto allocm = [&](size_t n) { u8* p = wsm + offm; offm += n; return p; };
    u8* m32 = allocm(4194304);
    u8* m16 = allocm(524288);
    u8* m8 = allocm(65536);
    u8* m4 = allocm(8192);
    u8* mD8 = allocm(65536);
    u8* mD16 = allocm(524288);
    u8* mD32 = allocm(4194304);

    const int N32 = 128 * 32768;
    const int N16 = 128 * 4096;
    const int N8 = 128 * 512;
    const int N4 = 128 * 64;
    auto gs = [](int n) { return dim3((n + 255) / 256); };
    auto rb = [](int n) { int bl = (n + 255) / 256; return dim3(bl > 512 ? 512 : bl); };
    dim3 blk(256);

    // masks
    mask_init_k<<<gs(N32), blk, 0, stream>>>(mraw, m32, N32);
    pool_k<16><<<gs(N16), blk, 0, stream>>>(m32, m16);
    pool_k<8><<<gs(N8), blk, 0, stream>>>(m16, m8);
    pool_k<4><<<gs(N4), blk, 0, stream>>>(m8, m4);

    // ---- encoder stage 0 @32^3 (BN stats via fused recompute; then 4 chunks of 32 samples) ----
    hipMemsetAsync(stats, 0, 128 * sizeof(double), stream);
    prep_reduce_k<<<512, blk, 0, stream>>>(vox, m32, wp, stats);
    bn_final_k<4><<<1, 64, 0, stream>>>(stats, g_e0, b_e0, params);
    for (int c = 0; c < 4; c++) {
        size_t o32 = (size_t)c * 32 * 32768;
        size_t o16 = (size_t)c * 32 * 4096;
        prep_bn_k<<<gs(32 * 32768), blk, 0, stream>>>(vox + o32, m32 + o32, wp, params, A);
        conv_k<3, 4, 4, 32, 32><<<gs(32 * 32768), blk, 0, stream>>>(A, ws_e0, m32 + o32, B);
        down_k<4, 8, 16, 32><<<gs(32 * 4096), blk, 0, stream>>>(B, wd_e0, m16 + o16, P + o16 * 8);
    }

    // ---- encoder stage 1 @16^3 ----
    hipMemsetAsync(stats, 0, 128 * sizeof(double), stream);
    bn_reduce_k<8><<<rb(N16), blk, 0, stream>>>(P, m16, N16, stats);
    bn_final_k<8><<<1, 64, 0, stream>>>(stats, g_e1, b_e1, params);
    convbn_k<8, 8, 16><<<gs(N16), blk, 0, stream>>>(P, ws_e1, m16, params, Q);
    down_k<8, 16, 8, 128><<<gs(N8), blk, 0, stream>>>(Q, wd_e1, m8, U);

    // ---- encoder stage 2 @8^3 ----
    hipMemsetAsync(stats, 0, 128 * sizeof(double), stream);
    bn_reduce_k<16><<<rb(N8), blk, 0, stream>>>(U, m8, N8, stats);
    bn_final_k<16><<<1, 64, 0, stream>>>(stats, g_e2, b_e2, params);
    convbn_k<16, 16, 8><<<gs(N8), blk, 0, stream>>>(U, ws_e2, m8, params, V);
    down_k<16, 32, 4, 128><<<gs(N4), blk, 0, stream>>>(V, wd_e2, m4, T);

    // ---- hidden ----
    hidden_k<<<gs(128 * 2048), blk, 0, stream>>>(T, out);

    // ---- decoder stage 0 (32->16, 4^3 -> 8^3), band gate delta=4e-7 ----
    hipMemsetAsync(stats, 0, 128 * sizeof(double), stream);
    bn_reduce_k<32><<<rb(N4), blk, 0, stream>>>(T, m4, N4, stats);
    bn_final_k<32><<<1, 64, 0, stream>>>(stats, g_d0, b_d0, params);
    upbn_k<32, 16, 4, 128><<<gs(N8), blk, 0, stream>>>(T, wu_d0, m4, params, U);
    conv3s_k<16, 16, 8, 128><<<gs(N8), blk, 0, stream>>>(U, ws3_d0, m4, mD8, V, 4e-7);
    conv_k<4, 16, 16, 8, 128><<<gs(N8), blk, 0, stream>>>(V, ws4_d0, mD8, U);

    // ---- decoder stage 1 (16->8, 8^3 -> 16^3), band gate delta=4e-7 ----
    hipMemsetAsync(stats, 0, 128 * sizeof(double), stream);
    bn_reduce_k<16><<<rb(N8), blk, 0, stream>>>(U, mD8, N8, stats);
    bn_final_k<16><<<1, 64, 0, stream>>>(stats, g_d1, b_d1, params);
    upbn_k<16, 8, 8, 128><<<gs(N16), blk, 0, stream>>>(U, wu_d1, mD8, params, P);
    conv3s_k<8, 8, 16, 128><<<gs(N16), blk, 0, stream>>>(P, ws3_d1, mD8, mD16, Q, 4e-7);
    conv_k<4, 8, 8, 16, 128><<<gs(N16), blk, 0, stream>>>(Q, ws4_d1, mD16, P);

    // ---- decoder stage 2 (8->4, 16^3 -> 32^3, 4 chunks of 32 samples), exact gate ----
    hipMemsetAsync(stats, 0, 128 * sizeof(double), stream);
    bn_reduce_k<8><<<rb(N16), blk, 0, stream>>>(P, mD16, N16, stats);
    bn_final_k<8><<<1, 64, 0, stream>>>(stats, g_d2, b_d2, params);
    for (int c = 0; c < 4; c++) {
        size_t o32 = (size_t)c * 32 * 32768;
        size_t o16 = (size_t)c * 32 * 4096;
        upbn_k<8, 4, 16, 32><<<gs(32 * 32768), blk, 0, stream>>>(P + o16 * 8, wu_d2, mD16 + o16, params, A);
        conv3s_k<4, 4, 32, 32><<<gs(32 * 32768), blk, 0, stream>>>(A, ws3_d2, mD16 + o16, mD32 + o32, B, 0.0);
        conv_k<4, 4, 4, 32, 32><<<gs(32 * 32768), blk, 0, stream>>>(B, ws4_d2, mD32 + o32, A);
        outconv_k<<<gs(32 * 32768), blk, 0, stream>>>(A, wo, mD32 + o32, out + 262144 + o32);
    }
}

// Round 10
// 3596.243 us; speedup vs baseline: 1.3430x; 1.3430x over previous
//
#include <hip/hip_runtime.h>

using u8 = unsigned char;

// ---------------- mask init: m = (maskraw == 0) ----------------
__global__ void mask_init_k(const int* __restrict__ mr, u8* __restrict__ m, int N) {
    int i = blockIdx.x * blockDim.x + threadIdx.x;
    if (i < N) m[i] = (mr[i] == 0) ? 1 : 0;
}

// ---------------- mask pool 2x2x2 (logical OR), full batch ----------------
template <int SO>
__global__ void pool_k(const u8* __restrict__ mi, u8* __restrict__ mo) {
    const int N = 128 * SO * SO * SO;
    constexpr int SI = 2 * SO;
    int v = blockIdx.x * blockDim.x + threadIdx.x;
    if (v >= N) return;
    int t = v;
    int x = t % SO; t /= SO;
    int y = t % SO; t /= SO;
    int z = t % SO;
    int n = t / SO;
    u8 m = 0;
    for (int kd = 0; kd < 2; kd++)
        for (int kh = 0; kh < 2; kh++)
            for (int kw = 0; kw < 2; kw++)
                m |= mi[((n * SI + 2 * z + kd) * SI + 2 * y + kh) * SI + 2 * x + kw];
    mo[v] = m;
}

// ---------------- prepare conv 1->4, k=3, masked input+output, full batch ----------------
__global__ void prep_k(const float* __restrict__ vox, const u8* __restrict__ m,
                       const float* __restrict__ wp, float* __restrict__ out) {
    const int N = 128 * 32768;
    int v = blockIdx.x * blockDim.x + threadIdx.x;
    if (v >= N) return;
    if (!m[v]) {
#pragma unroll
        for (int co = 0; co < 4; co++) out[(size_t)v * 4 + co] = 0.f;
        return;
    }
    int t = v;
    int x = t & 31; t >>= 5;
    int y = t & 31; t >>= 5;
    int z = t & 31;
    int n = t >> 5;
    double p[4] = {0, 0, 0, 0};
    for (int kd = 0; kd < 3; kd++) {
        int zz = z + kd - 1; if ((unsigned)zz >= 32u) continue;
        for (int kh = 0; kh < 3; kh++) {
            int yy = y + kh - 1; if ((unsigned)yy >= 32u) continue;
            for (int kw = 0; kw < 3; kw++) {
                int xx = x + kw - 1; if ((unsigned)xx >= 32u) continue;
                int sv = ((n * 32 + zz) * 32 + yy) * 32 + xx;
                if (!m[sv]) continue;
                double xv = (double)vox[sv];
                const float* w = wp + ((kd * 3 + kh) * 3 + kw) * 4;
#pragma unroll
                for (int co = 0; co < 4; co++) p[co] += xv * (double)w[co];
            }
        }
    }
#pragma unroll
    for (int co = 0; co < 4; co++) out[(size_t)v * 4 + co] = (float)p[co];
}

// ---------------- plain conv (input pre-masked/zeroed), k=3 pad(1,1) or k=4 pad(1,2) ----------------
template <int K, int CIN, int COUT, int S>
__global__ void conv_k(const float* __restrict__ in, const float* __restrict__ w,
                       const u8* __restrict__ outmask, float* __restrict__ out) {
    const int N = 128 * S * S * S;
    int v = blockIdx.x * blockDim.x + threadIdx.x;
    if (v >= N) return;
    if (!outmask[v]) {
#pragma unroll
        for (int co = 0; co < COUT; co++) out[(size_t)v * COUT + co] = 0.f;
        return;
    }
    int t = v;
    int x = t % S; t /= S;
    int y = t % S; t /= S;
    int z = t % S;
    int n = t / S;
    double acc[COUT];
#pragma unroll
    for (int co = 0; co < COUT; co++) acc[co] = 0.0;
    constexpr int PLO = (K - 1) / 2;
    for (int kd = 0; kd < K; kd++) {
        int zz = z + kd - PLO; if ((unsigned)zz >= (unsigned)S) continue;
        for (int kh = 0; kh < K; kh++) {
            int yy = y + kh - PLO; if ((unsigned)yy >= (unsigned)S) continue;
            for (int kw = 0; kw < K; kw++) {
                int xx = x + kw - PLO; if ((unsigned)xx >= (unsigned)S) continue;
                int sv = ((n * S + zz) * S + yy) * S + xx;
                const float* ip = in + (size_t)sv * CIN;
                const float* wpk = w + ((kd * K + kh) * K + kw) * CIN * COUT;
#pragma unroll
                for (int ci = 0; ci < CIN; ci++) {
                    double xv = (double)ip[ci];
#pragma unroll
                    for (int co = 0; co < COUT; co++) acc[co] += xv * (double)wpk[ci * COUT + co];
                }
            }
        }
    }
#pragma unroll
    for (int co = 0; co < COUT; co++) out[(size_t)v * COUT + co] = (float)acc[co];
}

// ---------------- conv k=3 with BN(affine+ReLU+mask) applied to input on load, full batch ----------------
template <int CIN, int COUT, int S>
__global__ void convbn_k(const float* __restrict__ in, const float* __restrict__ w,
                         const u8* __restrict__ mask, const double* __restrict__ params,
                         float* __restrict__ out) {
    const int N = 128 * S * S * S;
    int v = blockIdx.x * blockDim.x + threadIdx.x;
    if (v >= N) return;
    if (!mask[v]) {
#pragma unroll
        for (int co = 0; co < COUT; co++) out[(size_t)v * COUT + co] = 0.f;
        return;
    }
    int t = v;
    int x = t % S; t /= S;
    int y = t % S; t /= S;
    int z = t % S;
    int n = t / S;
    double acc[COUT];
#pragma unroll
    for (int co = 0; co < COUT; co++) acc[co] = 0.0;
    for (int kd = 0; kd < 3; kd++) {
        int zz = z + kd - 1; if ((unsigned)zz >= (unsigned)S) continue;
        for (int kh = 0; kh < 3; kh++) {
            int yy = y + kh - 1; if ((unsigned)yy >= (unsigned)S) continue;
            for (int kw = 0; kw < 3; kw++) {
                int xx = x + kw - 1; if ((unsigned)xx >= (unsigned)S) continue;
                int sv = ((n * S + zz) * S + yy) * S + xx;
                if (!mask[sv]) continue;
                const float* ip = in + (size_t)sv * CIN;
                const float* wpk = w + ((kd * 3 + kh) * 3 + kw) * CIN * COUT;
#pragma unroll
                for (int ci = 0; ci < CIN; ci++) {
                    double yv = fmax((double)ip[ci] * params[ci] + params[CIN + ci], 0.0);
#pragma unroll
                    for (int co = 0; co < COUT; co++) acc[co] += yv * (double)wpk[ci * COUT + co];
                }
            }
        }
    }
#pragma unroll
    for (int co = 0; co < COUT; co++) out[(size_t)v * COUT + co] = (float)acc[co];
}

// ---------------- conv k=3 + fused sparsify; gate = parent (half-res) mask; writes new mask ----------------
// Gate: active iff acc0 > -delta * sum|terms| (fp64). delta=0 -> exact reference rule.
template <int CIN, int COUT, int S>
__global__ void conv3s_k(const float* __restrict__ in, const float* __restrict__ w,
                         const u8* __restrict__ pmask, u8* __restrict__ nmask,
                         float* __restrict__ out, double delta) {
    const int N = 128 * S * S * S;
    constexpr int SP = S / 2;
    int v = blockIdx.x * blockDim.x + threadIdx.x;
    if (v >= N) return;
    int t = v;
    int x = t % S; t /= S;
    int y = t % S; t /= S;
    int z = t % S;
    int n = t / S;
    int pidx = ((n * SP + (z >> 1)) * SP + (y >> 1)) * SP + (x >> 1);
    if (!pmask[pidx]) {
        nmask[v] = 0;
#pragma unroll
        for (int co = 0; co < COUT; co++) out[(size_t)v * COUT + co] = 0.f;
        return;
    }
    double acc[COUT];
#pragma unroll
    for (int co = 0; co < COUT; co++) acc[co] = 0.0;
    double asum = 0.0;
    for (int kd = 0; kd < 3; kd++) {
        int zz = z + kd - 1; if ((unsigned)zz >= (unsigned)S) continue;
        for (int kh = 0; kh < 3; kh++) {
            int yy = y + kh - 1; if ((unsigned)yy >= (unsigned)S) continue;
            for (int kw = 0; kw < 3; kw++) {
                int xx = x + kw - 1; if ((unsigned)xx >= (unsigned)S) continue;
                int sv = ((n * S + zz) * S + yy) * S + xx;
                const float* ip = in + (size_t)sv * CIN;
                const float* wpk = w + ((kd * 3 + kh) * 3 + kw) * CIN * COUT;
#pragma unroll
                for (int ci = 0; ci < CIN; ci++) {
                    double xv = (double)ip[ci];
                    asum += fabs(xv * (double)wpk[ci * COUT + 0]);
#pragma unroll
                    for (int co = 0; co < COUT; co++) acc[co] += xv * (double)wpk[ci * COUT + co];
                }
            }
        }
    }
    u8 nm = (acc[0] > -delta * asum) ? 1 : 0;
    nmask[v] = nm;
#pragma unroll
    for (int co = 0; co < COUT; co++) out[(size_t)v * COUT + co] = nm ? (float)acc[co] : 0.f;
}

// ---------------- strided down conv k=2 s=2 (input pre-masked) ----------------
template <int CIN, int COUT, int SO>
__global__ void down_k(const float* __restrict__ in, const float* __restrict__ w,
                       const u8* __restrict__ outmask, float* __restrict__ out) {
    const int N = 128 * SO * SO * SO;
    constexpr int SI = 2 * SO;
    int v = blockIdx.x * blockDim.x + threadIdx.x;
    if (v >= N) return;
    if (!outmask[v]) {
#pragma unroll
        for (int co = 0; co < COUT; co++) out[(size_t)v * COUT + co] = 0.f;
        return;
    }
    int t = v;
    int x = t % SO; t /= SO;
    int y = t % SO; t /= SO;
    int z = t % SO;
    int n = t / SO;
    double acc[COUT];
#pragma unroll
    for (int co = 0; co < COUT; co++) acc[co] = 0.0;
    for (int kd = 0; kd < 2; kd++)
        for (int kh = 0; kh < 2; kh++)
            for (int kw = 0; kw < 2; kw++) {
                int sv = ((n * SI + 2 * z + kd) * SI + 2 * y + kh) * SI + 2 * x + kw;
                const float* ip = in + (size_t)sv * CIN;
                const float* wpk = w + ((kd * 2 + kh) * 2 + kw) * CIN * COUT;
#pragma unroll
                for (int ci = 0; ci < CIN; ci++) {
                    double xv = (double)ip[ci];
#pragma unroll
                    for (int co = 0; co < COUT; co++) acc[co] += xv * (double)wpk[ci * COUT + co];
                }
            }
#pragma unroll
    for (int co = 0; co < COUT; co++) out[(size_t)v * COUT + co] = (float)acc[co];
}

// ---------------- fused BN + transposed conv k=2 s=2: out[2j+r] = relu(aff(x[j]))*w[1-r] ----------------
template <int CIN, int COUT, int SI>
__global__ void upbn_k(const float* __restrict__ in, const float* __restrict__ w,
                       const u8* __restrict__ inmask, const double* __restrict__ params,
                       float* __restrict__ out) {
    constexpr int SO = 2 * SI;
    const int N = 128 * SO * SO * SO;
    int v = blockIdx.x * blockDim.x + threadIdx.x;
    if (v >= N) return;
    int t = v;
    int x = t % SO; t /= SO;
    int y = t % SO; t /= SO;
    int z = t % SO;
    int n = t / SO;
    int sv = ((n * SI + (z >> 1)) * SI + (y >> 1)) * SI + (x >> 1);
    if (!inmask[sv]) {
#pragma unroll
        for (int co = 0; co < COUT; co++) out[(size_t)v * COUT + co] = 0.f;
        return;
    }
    int tap = ((1 - (z & 1)) * 2 + (1 - (y & 1))) * 2 + (1 - (x & 1));
    const float* wpk = w + tap * CIN * COUT;
    const float* ip = in + (size_t)sv * CIN;
    double acc[COUT];
#pragma unroll
    for (int co = 0; co < COUT; co++) acc[co] = 0.0;
#pragma unroll
    for (int ci = 0; ci < CIN; ci++) {
        double yv = fmax((double)ip[ci] * params[ci] + params[CIN + ci], 0.0);
#pragma unroll
        for (int co = 0; co < COUT; co++) acc[co] += yv * (double)wpk[ci * COUT + co];
    }
#pragma unroll
    for (int co = 0; co < COUT; co++) out[(size_t)v * COUT + co] = (float)acc[co];
}

// ---------------- BN masked reduce (fp32 input, fp64 accum) ----------------
template <int C>
__global__ void bn_reduce_k(const float* __restrict__ x, const u8* __restrict__ m, int N,
                            double* __restrict__ stats) {
    double cnt = 0.0, sx[C], s2[C];
#pragma unroll
    for (int c = 0; c < C; c++) { sx[c] = 0.0; s2[c] = 0.0; }
    int stride = gridDim.x * blockDim.x;
    for (int v = blockIdx.x * blockDim.x + threadIdx.x; v < N; v += stride) {
        if (!m[v]) continue;
        cnt += 1.0;
#pragma unroll
        for (int c = 0; c < C; c++) {
            double xv = (double)x[(size_t)v * C + c];
            sx[c] += xv;
            s2[c] += xv * xv;
        }
    }
#pragma unroll
    for (int off = 32; off > 0; off >>= 1) {
        cnt += __shfl_down(cnt, off, 64);
#pragma unroll
        for (int c = 0; c < C; c++) {
            sx[c] += __shfl_down(sx[c], off, 64);
            s2[c] += __shfl_down(s2[c], off, 64);
        }
    }
    if ((threadIdx.x & 63) == 0) {
        atomicAdd(&stats[0], cnt);
#pragma unroll
        for (int c = 0; c < C; c++) {
            atomicAdd(&stats[1 + c], sx[c]);
            atomicAdd(&stats[1 + C + c], s2[c]);
        }
    }
}

// ---------------- BN finalize ----------------
template <int C>
__global__ void bn_final_k(const double* __restrict__ stats, const float* __restrict__ g,
                           const float* __restrict__ b, double* __restrict__ params) {
    int c = threadIdx.x;
    if (c >= C) return;
    double cnt = stats[0];
    if (cnt < 1.0) cnt = 1.0;
    double mean = stats[1 + c] / cnt;
    double var = stats[1 + C + c] / cnt - mean * mean;
    double sc = (double)g[c] / sqrt(var + 1e-4);
    params[c] = sc;
    params[C + c] = (double)b[c] - mean * sc;
}

// ---------------- final output conv k=3, 4->1, full batch, fp32 out ----------------
__global__ void outconv_k(const float* __restrict__ in, const float* __restrict__ w,
                          const u8* __restrict__ mask, float* __restrict__ out) {
    const int N = 128 * 32768;
    int v = blockIdx.x * blockDim.x + threadIdx.x;
    if (v >= N) return;
    if (!mask[v]) { out[v] = 0.f; return; }
    int t = v;
    int x = t & 31; t >>= 5;
    int y = t & 31; t >>= 5;
    int z = t & 31;
    int n = t >> 5;
    double acc = 0.0;
    for (int kd = 0; kd < 3; kd++) {
        int zz = z + kd - 1; if ((unsigned)zz >= 32u) continue;
        for (int kh = 0; kh < 3; kh++) {
            int yy = y + kh - 1; if ((unsigned)yy >= 32u) continue;
            for (int kw = 0; kw < 3; kw++) {
                int xx = x + kw - 1; if ((unsigned)xx >= 32u) continue;
                int sv = ((n * 32 + zz) * 32 + yy) * 32 + xx;
                const float* ip = in + (size_t)sv * 4;
                const float* wpk = w + ((kd * 3 + kh) * 3 + kw) * 4;
#pragma unroll
                for (int ci = 0; ci < 4; ci++) acc += (double)ip[ci] * (double)wpk[ci];
            }
        }
    }
    out[v] = (float)acc;
}

// ---------------- hidden: NDHWC (4^3, 32ch) -> NCDHW flat ----------------
__global__ void hidden_k(const float* __restrict__ x, float* __restrict__ out) {
    int i = blockIdx.x * blockDim.x + threadIdx.x;
    if (i >= 128 * 2048) return;
    int b = i >> 11;
    int r = i & 2047;
    int c = r >> 6;
    int s = r & 63;
    int d = s >> 4;
    int h = (s >> 2) & 3;
    int w = s & 3;
    out[i] = x[((((b * 4 + d) * 4 + h) * 4 + w) << 5) + c];
}

extern "C" void kernel_launch(void* const* d_in, const int* in_sizes, int n_in,
                              void* d_out, int out_size, void* d_ws, size_t ws_size,
                              hipStream_t stream) {
    const float* vox = (const float*)d_in[0];
    const int* mraw = (const int*)d_in[1];
    const float* wp = (const float*)d_in[2];
    const float* g_e0 = (const float*)d_in[3];
    const float* b_e0 = (const float*)d_in[4];
    const float* ws_e0 = (const float*)d_in[5];
    const float* wd_e0 = (const float*)d_in[6];
    const float* g_e1 = (const float*)d_in[7];
    const float* b_e1 = (const float*)d_in[8];
    const float* ws_e1 = (const float*)d_in[9];
    const float* wd_e1 = (const float*)d_in[10];
    const float* g_e2 = (const float*)d_in[11];
    const float* b_e2 = (const float*)d_in[12];
    const float* ws_e2 = (const float*)d_in[13];
    const float* wd_e2 = (const float*)d_in[14];
    const float* g_d0 = (const float*)d_in[15];
    const float* b_d0 = (const float*)d_in[16];
    const float* wu_d0 = (const float*)d_in[17];
    const float* ws3_d0 = (const float*)d_in[18];
    const float* ws4_d0 = (const float*)d_in[19];
    const float* g_d1 = (const float*)d_in[20];
    const float* b_d1 = (const float*)d_in[21];
    const float* wu_d1 = (const float*)d_in[22];
    const float* ws3_d1 = (const float*)d_in[23];
    const float* ws4_d1 = (const float*)d_in[24];
    const float* g_d2 = (const float*)d_in[25];
    const float* b_d2 = (const float*)d_in[26];
    const float* wu_d2 = (const float*)d_in[27];
    const float* ws3_d2 = (const float*)d_in[28];
    const float* ws4_d2 = (const float*)d_in[29];
    const float* wo = (const float*)d_in[30];
    float* out = (float*)d_out;

    // ---- workspace: fp32 tensors + fp64 stats + u8 masks (~153 MB) ----
    float* wsf = (float*)d_ws;
    size_t offf = 0;
    auto allocf = [&](size_t n) { float* p = wsf + offf; offf += n; return p; };
    float* R1 = allocf(16777216);  // 128*32^3*4ch fp32 (aliases 16^3*8ch in head)
    float* R2 = allocf(16777216);
    float* S1 = allocf(1048576);   // 128*8^3*16ch
    float* S2 = allocf(1048576);
    float* T = allocf(262144);     // 128*4^3*32ch
    double* wsd = (double*)(wsf + offf);
    double* stats = wsd;
    double* params = wsd + 128;
    u8* wsm = (u8*)(wsd + 256);
    size_t offm = 0;
    auto allocm = [&](size_t n) { u8* p = wsm + offm; offm += n; return p; };
    u8* m32 = allocm(4194304);
    u8* m16 = allocm(524288);
    u8* m8 = allocm(65536);
    u8* m4 = allocm(8192);
    u8* mD8 = allocm(65536);
    u8* mD16 = allocm(524288);
    u8* mD32 = allocm(4194304);

    const int N32 = 128 * 32768;
    const int N16 = 128 * 4096;
    const int N8 = 128 * 512;
    const int N4 = 128 * 64;
    auto gs = [](int n) { return dim3((n + 255) / 256); };
    auto rb = [](int n) { int bl = (n + 255) / 256; return dim3(bl > 1024 ? 1024 : bl); };
    dim3 blk(256);

    // masks
    mask_init_k<<<gs(N32), blk, 0, stream>>>(mraw, m32, N32);
    pool_k<16><<<gs(N16), blk, 0, stream>>>(m32, m16);
    pool_k<8><<<gs(N8), blk, 0, stream>>>(m16, m8);
    pool_k<4><<<gs(N4), blk, 0, stream>>>(m8, m4);

    // ---- encoder stage 0 @32^3, full batch ----
    prep_k<<<gs(N32), blk, 0, stream>>>(vox, m32, wp, R1);
    hipMemsetAsync(stats, 0, 128 * sizeof(double), stream);
    bn_reduce_k<4><<<rb(N32), blk, 0, stream>>>(R1, m32, N32, stats);
    bn_final_k<4><<<1, 64, 0, stream>>>(stats, g_e0, b_e0, params);
    convbn_k<4, 4, 32><<<gs(N32), blk, 0, stream>>>(R1, ws_e0, m32, params, R2);
    down_k<4, 8, 16><<<gs(N16), blk, 0, stream>>>(R2, wd_e0, m16, R1);

    // ---- encoder stage 1 @16^3 (P16 = R1 head, Q16 = R2 head) ----
    hipMemsetAsync(stats, 0, 128 * sizeof(double), stream);
    bn_reduce_k<8><<<rb(N16), blk, 0, stream>>>(R1, m16, N16, stats);
    bn_final_k<8><<<1, 64, 0, stream>>>(stats, g_e1, b_e1, params);
    convbn_k<8, 8, 16><<<gs(N16), blk, 0, stream>>>(R1, ws_e1, m16, params, R2);
    down_k<8, 16, 8><<<gs(N8), blk, 0, stream>>>(R2, wd_e1, m8, S1);

    // ---- encoder stage 2 @8^3 ----
    hipMemsetAsync(stats, 0, 128 * sizeof(double), stream);
    bn_reduce_k<16><<<rb(N8), blk, 0, stream>>>(S1, m8, N8, stats);
    bn_final_k<16><<<1, 64, 0, stream>>>(stats, g_e2, b_e2, params);
    convbn_k<16, 16, 8><<<gs(N8), blk, 0, stream>>>(S1, ws_e2, m8, params, S2);
    down_k<16, 32, 4><<<gs(N4), blk, 0, stream>>>(S2, wd_e2, m4, T);

    // ---- hidden ----
    hidden_k<<<gs(128 * 2048), blk, 0, stream>>>(T, out);

    // ---- decoder stage 0 (32->16, 4^3 -> 8^3), band gate delta=4e-7 ----
    hipMemsetAsync(stats, 0, 128 * sizeof(double), stream);
    bn_reduce_k<32><<<rb(N4), blk, 0, stream>>>(T, m4, N4, stats);
    bn_final_k<32><<<1, 64, 0, stream>>>(stats, g_d0, b_d0, params);
    upbn_k<32, 16, 4><<<gs(N8), blk, 0, stream>>>(T, wu_d0, m4, params, S1);
    conv3s_k<16, 16, 8><<<gs(N8), blk, 0, stream>>>(S1, ws3_d0, m4, mD8, S2, 4e-7);
    conv_k<4, 16, 16, 8><<<gs(N8), blk, 0, stream>>>(S2, ws4_d0, mD8, S1);

    // ---- decoder stage 1 (16->8, 8^3 -> 16^3), band gate delta=4e-7 ----
    hipMemsetAsync(stats, 0, 128 * sizeof(double), stream);
    bn_reduce_k<16><<<rb(N8), blk, 0, stream>>>(S1, mD8, N8, stats);
    bn_final_k<16><<<1, 64, 0, stream>>>(stats, g_d1, b_d1, params);
    upbn_k<16, 8, 8><<<gs(N16), blk, 0, stream>>>(S1, wu_d1, mD8, params, R1);
    conv3s_k<8, 8, 16><<<gs(N16), blk, 0, stream>>>(R1, ws3_d1, mD8, mD16, R2, 4e-7);
    conv_k<4, 8, 8, 16><<<gs(N16), blk, 0, stream>>>(R2, ws4_d1, mD16, R1);

    // ---- decoder stage 2 (8->4, 16^3 -> 32^3), exact gate ----
    hipMemsetAsync(stats, 0, 128 * sizeof(double), stream);
    bn_reduce_k<8><<<rb(N16), blk, 0, stream>>>(R1, mD16, N16, stats);
    bn_final_k<8><<<1, 64, 0, stream>>>(stats, g_d2, b_d2, params);
    upbn_k<8, 4, 16><<<gs(N32), blk, 0, stream>>>(R1, wu_d2, mD16, params, R2);
    conv3s_k<4, 4, 32><<<gs(N32), blk, 0, stream>>>(R2, ws3_d2, mD16, mD32, R1, 0.0);
    conv_k<4, 4, 4, 32><<<gs(N32), blk, 0, stream>>>(R1, ws4_d2, mD32, R2);
    outconv_k<<<gs(N32), blk, 0, stream>>>(R2, wo, mD32, out + 262144);
}

// Round 11
// 2131.767 us; speedup vs baseline: 2.2656x; 1.6870x over previous
//
#include <hip/hip_runtime.h>

using u8 = unsigned char;

// ---------------- mask init: m = (maskraw == 0) ----------------
__global__ void mask_init_k(const int* __restrict__ mr, u8* __restrict__ m, int N) {
    int i = blockIdx.x * blockDim.x + threadIdx.x;
    if (i < N) m[i] = (mr[i] == 0) ? 1 : 0;
}

// ---------------- mask pool 2x2x2 (logical OR), full batch ----------------
template <int SO>
__global__ void pool_k(const u8* __restrict__ mi, u8* __restrict__ mo) {
    const int N = 128 * SO * SO * SO;
    constexpr int SI = 2 * SO;
    int v = blockIdx.x * blockDim.x + threadIdx.x;
    if (v >= N) return;
    int t = v;
    int x = t % SO; t /= SO;
    int y = t % SO; t /= SO;
    int z = t % SO;
    int n = t / SO;
    u8 m = 0;
    for (int kd = 0; kd < 2; kd++)
        for (int kh = 0; kh < 2; kh++)
            for (int kw = 0; kw < 2; kw++)
                m |= mi[((n * SI + 2 * z + kd) * SI + 2 * y + kh) * SI + 2 * x + kw];
    mo[v] = m;
}

// ---------------- prepare conv 1->4, k=3, masked input+output, full batch ----------------
__global__ void prep_k(const float* __restrict__ vox, const u8* __restrict__ m,
                       const float* __restrict__ wp, float* __restrict__ out) {
    const int N = 128 * 32768;
    int v = blockIdx.x * blockDim.x + threadIdx.x;
    if (v >= N) return;
    if (!m[v]) {
#pragma unroll
        for (int co = 0; co < 4; co++) out[(size_t)v * 4 + co] = 0.f;
        return;
    }
    int t = v;
    int x = t & 31; t >>= 5;
    int y = t & 31; t >>= 5;
    int z = t & 31;
    int n = t >> 5;
    double p[4] = {0, 0, 0, 0};
    for (int kd = 0; kd < 3; kd++) {
        int zz = z + kd - 1; if ((unsigned)zz >= 32u) continue;
        for (int kh = 0; kh < 3; kh++) {
            int yy = y + kh - 1; if ((unsigned)yy >= 32u) continue;
            for (int kw = 0; kw < 3; kw++) {
                int xx = x + kw - 1; if ((unsigned)xx >= 32u) continue;
                int sv = ((n * 32 + zz) * 32 + yy) * 32 + xx;
                if (!m[sv]) continue;
                double xv = (double)vox[sv];
                const float* w = wp + ((kd * 3 + kh) * 3 + kw) * 4;
#pragma unroll
                for (int co = 0; co < 4; co++) p[co] += xv * (double)w[co];
            }
        }
    }
#pragma unroll
    for (int co = 0; co < 4; co++) out[(size_t)v * 4 + co] = (float)p[co];
}

// ---------------- plain conv (input pre-masked/zeroed), k=3 pad(1,1) or k=4 pad(1,2) ----------------
template <int K, int CIN, int COUT, int S>
__global__ void conv_k(const float* __restrict__ in, const float* __restrict__ w,
                       const u8* __restrict__ outmask, float* __restrict__ out) {
    const int N = 128 * S * S * S;
    int v = blockIdx.x * blockDim.x + threadIdx.x;
    if (v >= N) return;
    if (!outmask[v]) {
#pragma unroll
        for (int co = 0; co < COUT; co++) out[(size_t)v * COUT + co] = 0.f;
        return;
    }
    int t = v;
    int x = t % S; t /= S;
    int y = t % S; t /= S;
    int z = t % S;
    int n = t / S;
    double acc[COUT];
#pragma unroll
    for (int co = 0; co < COUT; co++) acc[co] = 0.0;
    constexpr int PLO = (K - 1) / 2;
    for (int kd = 0; kd < K; kd++) {
        int zz = z + kd - PLO; if ((unsigned)zz >= (unsigned)S) continue;
        for (int kh = 0; kh < K; kh++) {
            int yy = y + kh - PLO; if ((unsigned)yy >= (unsigned)S) continue;
            for (int kw = 0; kw < K; kw++) {
                int xx = x + kw - PLO; if ((unsigned)xx >= (unsigned)S) continue;
                int sv = ((n * S + zz) * S + yy) * S + xx;
                const float* ip = in + (size_t)sv * CIN;
                const float* wpk = w + ((kd * K + kh) * K + kw) * CIN * COUT;
#pragma unroll
                for (int ci = 0; ci < CIN; ci++) {
                    double xv = (double)ip[ci];
#pragma unroll
                    for (int co = 0; co < COUT; co++) acc[co] += xv * (double)wpk[ci * COUT + co];
                }
            }
        }
    }
#pragma unroll
    for (int co = 0; co < COUT; co++) out[(size_t)v * COUT + co] = (float)acc[co];
}

// ---------------- conv k=3 with BN(affine+ReLU+mask) applied to input on load, full batch ----------------
template <int CIN, int COUT, int S>
__global__ void convbn_k(const float* __restrict__ in, const float* __restrict__ w,
                         const u8* __restrict__ mask, const double* __restrict__ params,
                         float* __restrict__ out) {
    const int N = 128 * S * S * S;
    int v = blockIdx.x * blockDim.x + threadIdx.x;
    if (v >= N) return;
    if (!mask[v]) {
#pragma unroll
        for (int co = 0; co < COUT; co++) out[(size_t)v * COUT + co] = 0.f;
        return;
    }
    int t = v;
    int x = t % S; t /= S;
    int y = t % S; t /= S;
    int z = t % S;
    int n = t / S;
    double acc[COUT];
#pragma unroll
    for (int co = 0; co < COUT; co++) acc[co] = 0.0;
    for (int kd = 0; kd < 3; kd++) {
        int zz = z + kd - 1; if ((unsigned)zz >= (unsigned)S) continue;
        for (int kh = 0; kh < 3; kh++) {
            int yy = y + kh - 1; if ((unsigned)yy >= (unsigned)S) continue;
            for (int kw = 0; kw < 3; kw++) {
                int xx = x + kw - 1; if ((unsigned)xx >= (unsigned)S) continue;
                int sv = ((n * S + zz) * S + yy) * S + xx;
                if (!mask[sv]) continue;
                const float* ip = in + (size_t)sv * CIN;
                const float* wpk = w + ((kd * 3 + kh) * 3 + kw) * CIN * COUT;
#pragma unroll
                for (int ci = 0; ci < CIN; ci++) {
                    double yv = fmax((double)ip[ci] * params[ci] + params[CIN + ci], 0.0);
#pragma unroll
                    for (int co = 0; co < COUT; co++) acc[co] += yv * (double)wpk[ci * COUT + co];
                }
            }
        }
    }
#pragma unroll
    for (int co = 0; co < COUT; co++) out[(size_t)v * COUT + co] = (float)acc[co];
}

// ---------------- conv k=3 + fused sparsify; gate = parent (half-res) mask; writes new mask ----------------
// Gate: active iff acc0 > -delta * sum|terms| (fp64). delta=0 -> exact reference rule.
template <int CIN, int COUT, int S>
__global__ void conv3s_k(const float* __restrict__ in, const float* __restrict__ w,
                         const u8* __restrict__ pmask, u8* __restrict__ nmask,
                         float* __restrict__ out, double delta) {
    const int N = 128 * S * S * S;
    constexpr int SP = S / 2;
    int v = blockIdx.x * blockDim.x + threadIdx.x;
    if (v >= N) return;
    int t = v;
    int x = t % S; t /= S;
    int y = t % S; t /= S;
    int z = t % S;
    int n = t / S;
    int pidx = ((n * SP + (z >> 1)) * SP + (y >> 1)) * SP + (x >> 1);
    if (!pmask[pidx]) {
        nmask[v] = 0;
#pragma unroll
        for (int co = 0; co < COUT; co++) out[(size_t)v * COUT + co] = 0.f;
        return;
    }
    double acc[COUT];
#pragma unroll
    for (int co = 0; co < COUT; co++) acc[co] = 0.0;
    double asum = 0.0;
    for (int kd = 0; kd < 3; kd++) {
        int zz = z + kd - 1; if ((unsigned)zz >= (unsigned)S) continue;
        for (int kh = 0; kh < 3; kh++) {
            int yy = y + kh - 1; if ((unsigned)yy >= (unsigned)S) continue;
            for (int kw = 0; kw < 3; kw++) {
                int xx = x + kw - 1; if ((unsigned)xx >= (unsigned)S) continue;
                int sv = ((n * S + zz) * S + yy) * S + xx;
                const float* ip = in + (size_t)sv * CIN;
                const float* wpk = w + ((kd * 3 + kh) * 3 + kw) * CIN * COUT;
#pragma unroll
                for (int ci = 0; ci < CIN; ci++) {
                    double xv = (double)ip[ci];
                    asum += fabs(xv * (double)wpk[ci * COUT + 0]);
#pragma unroll
                    for (int co = 0; co < COUT; co++) acc[co] += xv * (double)wpk[ci * COUT + co];
                }
            }
        }
    }
    u8 nm = (acc[0] > -delta * asum) ? 1 : 0;
    nmask[v] = nm;
#pragma unroll
    for (int co = 0; co < COUT; co++) out[(size_t)v * COUT + co] = nm ? (float)acc[co] : 0.f;
}

// ---------------- strided down conv k=2 s=2 (input pre-masked) ----------------
template <int CIN, int COUT, int SO>
__global__ void down_k(const float* __restrict__ in, const float* __restrict__ w,
                       const u8* __restrict__ outmask, float* __restrict__ out) {
    const int N = 128 * SO * SO * SO;
    constexpr int SI = 2 * SO;
    int v = blockIdx.x * blockDim.x + threadIdx.x;
    if (v >= N) return;
    if (!outmask[v]) {
#pragma unroll
        for (int co = 0; co < COUT; co++) out[(size_t)v * COUT + co] = 0.f;
        return;
    }
    int t = v;
    int x = t % SO; t /= SO;
    int y = t % SO; t /= SO;
    int z = t % SO;
    int n = t / SO;
    double acc[COUT];
#pragma unroll
    for (int co = 0; co < COUT; co++) acc[co] = 0.0;
    for (int kd = 0; kd < 2; kd++)
        for (int kh = 0; kh < 2; kh++)
            for (int kw = 0; kw < 2; kw++) {
                int sv = ((n * SI + 2 * z + kd) * SI + 2 * y + kh) * SI + 2 * x + kw;
                const float* ip = in + (size_t)sv * CIN;
                const float* wpk = w + ((kd * 2 + kh) * 2 + kw) * CIN * COUT;
#pragma unroll
                for (int ci = 0; ci < CIN; ci++) {
                    double xv = (double)ip[ci];
#pragma unroll
                    for (int co = 0; co < COUT; co++) acc[co] += xv * (double)wpk[ci * COUT + co];
                }
            }
#pragma unroll
    for (int co = 0; co < COUT; co++) out[(size_t)v * COUT + co] = (float)acc[co];
}

// ---------------- fused BN + transposed conv k=2 s=2: out[2j+r] = relu(aff(x[j]))*w[1-r] ----------------
template <int CIN, int COUT, int SI>
__global__ void upbn_k(const float* __restrict__ in, const float* __restrict__ w,
                       const u8* __restrict__ inmask, const double* __restrict__ params,
                       float* __restrict__ out) {
    constexpr int SO = 2 * SI;
    const int N = 128 * SO * SO * SO;
    int v = blockIdx.x * blockDim.x + threadIdx.x;
    if (v >= N) return;
    int t = v;
    int x = t % SO; t /= SO;
    int y = t % SO; t /= SO;
    int z = t % SO;
    int n = t / SO;
    int sv = ((n * SI + (z >> 1)) * SI + (y >> 1)) * SI + (x >> 1);
    if (!inmask[sv]) {
#pragma unroll
        for (int co = 0; co < COUT; co++) out[(size_t)v * COUT + co] = 0.f;
        return;
    }
    int tap = ((1 - (z & 1)) * 2 + (1 - (y & 1))) * 2 + (1 - (x & 1));
    const float* wpk = w + tap * CIN * COUT;
    const float* ip = in + (size_t)sv * CIN;
    double acc[COUT];
#pragma unroll
    for (int co = 0; co < COUT; co++) acc[co] = 0.0;
#pragma unroll
    for (int ci = 0; ci < CIN; ci++) {
        double yv = fmax((double)ip[ci] * params[ci] + params[CIN + ci], 0.0);
#pragma unroll
        for (int co = 0; co < COUT; co++) acc[co] += yv * (double)wpk[ci * COUT + co];
    }
#pragma unroll
    for (int co = 0; co < COUT; co++) out[(size_t)v * COUT + co] = (float)acc[co];
}

// ---------------- BN masked reduce: wave shuffle -> LDS block reduce -> 1 atomic set per block ----------------
template <int C>
__global__ void bn_reduce_k(const float* __restrict__ x, const u8* __restrict__ m, int N,
                            double* __restrict__ stats) {
    double cnt = 0.0, sx[C], s2[C];
#pragma unroll
    for (int c = 0; c < C; c++) { sx[c] = 0.0; s2[c] = 0.0; }
    int stride = gridDim.x * blockDim.x;
    for (int v = blockIdx.x * blockDim.x + threadIdx.x; v < N; v += stride) {
        if (!m[v]) continue;
        cnt += 1.0;
#pragma unroll
        for (int c = 0; c < C; c++) {
            double xv = (double)x[(size_t)v * C + c];
            sx[c] += xv;
            s2[c] += xv * xv;
        }
    }
#pragma unroll
    for (int off = 32; off > 0; off >>= 1) {
        cnt += __shfl_down(cnt, off, 64);
#pragma unroll
        for (int c = 0; c < C; c++) {
            sx[c] += __shfl_down(sx[c], off, 64);
            s2[c] += __shfl_down(s2[c], off, 64);
        }
    }
    __shared__ double sbuf[4][2 * C + 1];
    int wave = threadIdx.x >> 6;
    if ((threadIdx.x & 63) == 0) {
        sbuf[wave][0] = cnt;
#pragma unroll
        for (int c = 0; c < C; c++) {
            sbuf[wave][1 + c] = sx[c];
            sbuf[wave][1 + C + c] = s2[c];
        }
    }
    __syncthreads();
    if (threadIdx.x == 0) {
        double tcnt = 0.0, tsx[C], ts2[C];
#pragma unroll
        for (int c = 0; c < C; c++) { tsx[c] = 0.0; ts2[c] = 0.0; }
        for (int wv = 0; wv < 4; wv++) {
            tcnt += sbuf[wv][0];
#pragma unroll
            for (int c = 0; c < C; c++) {
                tsx[c] += sbuf[wv][1 + c];
                ts2[c] += sbuf[wv][1 + C + c];
            }
        }
        atomicAdd(&stats[0], tcnt);
#pragma unroll
        for (int c = 0; c < C; c++) {
            atomicAdd(&stats[1 + c], tsx[c]);
            atomicAdd(&stats[1 + C + c], ts2[c]);
        }
    }
}

// ---------------- BN finalize ----------------
template <int C>
__global__ void bn_final_k(const double* __restrict__ stats, const float* __restrict__ g,
                           const float* __restrict__ b, double* __restrict__ params) {
    int c = threadIdx.x;
    if (c >= C) return;
    double cnt = stats[0];
    if (cnt < 1.0) cnt = 1.0;
    double mean = stats[1 + c] / cnt;
    double var = stats[1 + C + c] / cnt - mean * mean;
    double sc = (double)g[c] / sqrt(var + 1e-4);
    params[c] = sc;
    params[C + c] = (double)b[c] - mean * sc;
}

// ---------------- final output conv k=3, 4->1, full batch, fp32 out ----------------
__global__ void outconv_k(const float* __restrict__ in, const float* __restrict__ w,
                          const u8* __restrict__ mask, float* __restrict__ out) {
    const int N = 128 * 32768;
    int v = blockIdx.x * blockDim.x + threadIdx.x;
    if (v >= N) return;
    if (!mask[v]) { out[v] = 0.f; return; }
    int t = v;
    int x = t & 31; t >>= 5;
    int y = t & 31; t >>= 5;
    int z = t & 31;
    int n = t >> 5;
    double acc = 0.0;
    for (int kd = 0; kd < 3; kd++) {
        int zz = z + kd - 1; if ((unsigned)zz >= 32u) continue;
        for (int kh = 0; kh < 3; kh++) {
            int yy = y + kh - 1; if ((unsigned)yy >= 32u) continue;
            for (int kw = 0; kw < 3; kw++) {
                int xx = x + kw - 1; if ((unsigned)xx >= 32u) continue;
                int sv = ((n * 32 + zz) * 32 + yy) * 32 + xx;
                const float* ip = in + (size_t)sv * 4;
                const float* wpk = w + ((kd * 3 + kh) * 3 + kw) * 4;
#pragma unroll
                for (int ci = 0; ci < 4; ci++) acc += (double)ip[ci] * (double)wpk[ci];
            }
        }
    }
    out[v] = (float)acc;
}

// ---------------- hidden: NDHWC (4^3, 32ch) -> NCDHW flat ----------------
__global__ void hidden_k(const float* __restrict__ x, float* __restrict__ out) {
    int i = blockIdx.x * blockDim.x + threadIdx.x;
    if (i >= 128 * 2048) return;
    int b = i >> 11;
    int r = i & 2047;
    int c = r >> 6;
    int s = r & 63;
    int d = s >> 4;
    int h = (s >> 2) & 3;
    int w = s & 3;
    out[i] = x[((((b * 4 + d) * 4 + h) * 4 + w) << 5) + c];
}

extern "C" void kernel_launch(void* const* d_in, const int* in_sizes, int n_in,
                              void* d_out, int out_size, void* d_ws, size_t ws_size,
                              hipStream_t stream) {
    const float* vox = (const float*)d_in[0];
    const int* mraw = (const int*)d_in[1];
    const float* wp = (const float*)d_in[2];
    const float* g_e0 = (const float*)d_in[3];
    const float* b_e0 = (const float*)d_in[4];
    const float* ws_e0 = (const float*)d_in[5];
    const float* wd_e0 = (const float*)d_in[6];
    const float* g_e1 = (const float*)d_in[7];
    const float* b_e1 = (const float*)d_in[8];
    const float* ws_e1 = (const float*)d_in[9];
    const float* wd_e1 = (const float*)d_in[10];
    const float* g_e2 = (const float*)d_in[11];
    const float* b_e2 = (const float*)d_in[12];
    const float* ws_e2 = (const float*)d_in[13];
    const float* wd_e2 = (const float*)d_in[14];
    const float* g_d0 = (const float*)d_in[15];
    const float* b_d0 = (const float*)d_in[16];
    const float* wu_d0 = (const float*)d_in[17];
    const float* ws3_d0 = (const float*)d_in[18];
    const float* ws4_d0 = (const float*)d_in[19];
    const float* g_d1 = (const float*)d_in[20];
    const float* b_d1 = (const float*)d_in[21];
    const float* wu_d1 = (const float*)d_in[22];
    const float* ws3_d1 = (const float*)d_in[23];
    const float* ws4_d1 = (const float*)d_in[24];
    const float* g_d2 = (const float*)d_in[25];
    const float* b_d2 = (const float*)d_in[26];
    const float* wu_d2 = (const float*)d_in[27];
    const float* ws3_d2 = (const float*)d_in[28];
    const float* ws4_d2 = (const float*)d_in[29];
    const float* wo = (const float*)d_in[30];
    float* out = (float*)d_out;

    // ---- workspace: fp32 tensors + fp64 stats + u8 masks (~153 MB) ----
    float* wsf = (float*)d_ws;
    size_t offf = 0;
    auto allocf = [&](size_t n) { float* p = wsf + offf; offf += n; return p; };
    float* R1 = allocf(16777216);  // 128*32^3*4ch fp32 (head aliases 16^3*8ch)
    float* R2 = allocf(16777216);
    float* S1 = allocf(1048576);   // 128*8^3*16ch
    float* S2 = allocf(1048576);
    float* T = allocf(262144);     // 128*4^3*32ch
    double* wsd = (double*)(wsf + offf);
    double* stats = wsd;
    double* params = wsd + 128;
    u8* wsm = (u8*)(wsd + 256);
    size_t offm = 0;
    auto allocm = [&](size_t n) { u8* p = wsm + offm; offm += n; return p; };
    u8* m32 = allocm(4194304);
    u8* m16 = allocm(524288);
    u8* m8 = allocm(65536);
    u8* m4 = allocm(8192);
    u8* mD8 = allocm(65536);
    u8* mD16 = allocm(524288);
    u8* mD32 = allocm(4194304);

    const int N32 = 128 * 32768;
    const int N16 = 128 * 4096;
    const int N8 = 128 * 512;
    const int N4 = 128 * 64;
    auto gs = [](int n) { return dim3((n + 255) / 256); };
    // bn_reduce grid: cap at 256 blocks -> at most 256 atomic conflicts per address
    auto rb = [](int n) { int bl = (n + 255) / 256; return dim3(bl > 256 ? 256 : bl); };
    dim3 blk(256);

    // masks
    mask_init_k<<<gs(N32), blk, 0, stream>>>(mraw, m32, N32);
    pool_k<16><<<gs(N16), blk, 0, stream>>>(m32, m16);
    pool_k<8><<<gs(N8), blk, 0, stream>>>(m16, m8);
    pool_k<4><<<gs(N4), blk, 0, stream>>>(m8, m4);

    // ---- encoder stage 0 @32^3, full batch ----
    prep_k<<<gs(N32), blk, 0, stream>>>(vox, m32, wp, R1);
    hipMemsetAsync(stats, 0, 128 * sizeof(double), stream);
    bn_reduce_k<4><<<rb(N32), blk, 0, stream>>>(R1, m32, N32, stats);
    bn_final_k<4><<<1, 64, 0, stream>>>(stats, g_e0, b_e0, params);
    convbn_k<4, 4, 32><<<gs(N32), blk, 0, stream>>>(R1, ws_e0, m32, params, R2);
    down_k<4, 8, 16><<<gs(N16), blk, 0, stream>>>(R2, wd_e0, m16, R1);

    // ---- encoder stage 1 @16^3 ----
    hipMemsetAsync(stats, 0, 128 * sizeof(double), stream);
    bn_reduce_k<8><<<rb(N16), blk, 0, stream>>>(R1, m16, N16, stats);
    bn_final_k<8><<<1, 64, 0, stream>>>(stats, g_e1, b_e1, params);
    convbn_k<8, 8, 16><<<gs(N16), blk, 0, stream>>>(R1, ws_e1, m16, params, R2);
    down_k<8, 16, 8><<<gs(N8), blk, 0, stream>>>(R2, wd_e1, m8, S1);

    // ---- encoder stage 2 @8^3 ----
    hipMemsetAsync(stats, 0, 128 * sizeof(double), stream);
    bn_reduce_k<16><<<rb(N8), blk, 0, stream>>>(S1, m8, N8, stats);
    bn_final_k<16><<<1, 64, 0, stream>>>(stats, g_e2, b_e2, params);
    convbn_k<16, 16, 8><<<gs(N8), blk, 0, stream>>>(S1, ws_e2, m8, params, S2);
    down_k<16, 32, 4><<<gs(N4), blk, 0, stream>>>(S2, wd_e2, m4, T);

    // ---- hidden ----
    hidden_k<<<gs(128 * 2048), blk, 0, stream>>>(T, out);

    // ---- decoder stage 0 (32->16, 4^3 -> 8^3), band gate delta=4e-7 ----
    hipMemsetAsync(stats, 0, 128 * sizeof(double), stream);
    bn_reduce_k<32><<<rb(N4), blk, 0, stream>>>(T, m4, N4, stats);
    bn_final_k<32><<<1, 64, 0, stream>>>(stats, g_d0, b_d0, params);
    upbn_k<32, 16, 4><<<gs(N8), blk, 0, stream>>>(T, wu_d0, m4, params, S1);
    conv3s_k<16, 16, 8><<<gs(N8), blk, 0, stream>>>(S1, ws3_d0, m4, mD8, S2, 4e-7);
    conv_k<4, 16, 16, 8><<<gs(N8), blk, 0, stream>>>(S2, ws4_d0, mD8, S1);

    // ---- decoder stage 1 (16->8, 8^3 -> 16^3), band gate delta=4e-7 ----
    hipMemsetAsync(stats, 0, 128 * sizeof(double), stream);
    bn_reduce_k<16><<<rb(N8), blk, 0, stream>>>(S1, mD8, N8, stats);
    bn_final_k<16><<<1, 64, 0, stream>>>(stats, g_d1, b_d1, params);
    upbn_k<16, 8, 8><<<gs(N16), blk, 0, stream>>>(S1, wu_d1, mD8, params, R1);
    conv3s_k<8, 8, 16><<<gs(N16), blk, 0, stream>>>(R1, ws3_d1, mD8, mD16, R2, 4e-7);
    conv_k<4, 8, 8, 16><<<gs(N16), blk, 0, stream>>>(R2, ws4_d1, mD16, R1);

    // ---- decoder stage 2 (8->4, 16^3 -> 32^3), exact gate ----
    hipMemsetAsync(stats, 0, 128 * sizeof(double), stream);
    bn_reduce_k<8><<<rb(N16), blk, 0, stream>>>(R1, mD16, N16, stats);
    bn_final_k<8><<<1, 64, 0, stream>>>(stats, g_d2, b_d2, params);
    upbn_k<8, 4, 16><<<gs(N32), blk, 0, stream>>>(R1, wu_d2, mD16, params, R2);
    conv3s_k<4, 4, 32><<<gs(N32), blk, 0, stream>>>(R2, ws3_d2, mD16, mD32, R1, 0.0);
    conv_k<4, 4, 4, 32><<<gs(N32), blk, 0, stream>>>(R1, ws4_d2, mD32, R2);
    outconv_k<<<gs(N32), blk, 0, stream>>>(R2, wo, mD32, out + 262144);
}

// Round 13
// 1767.154 us; speedup vs baseline: 2.7331x; 1.2063x over previous
//
#include <hip/hip_runtime.h>

using u8 = unsigned char;

// ---------------- mask init: m = (maskraw == 0) ----------------
__global__ void mask_init_k(const int* __restrict__ mr, u8* __restrict__ m, int N) {
    int i = blockIdx.x * blockDim.x + threadIdx.x;
    if (i < N) m[i] = (mr[i] == 0) ? 1 : 0;
}

// ---------------- mask pool 2x2x2 (logical OR), full batch ----------------
template <int SO>
__global__ void pool_k(const u8* __restrict__ mi, u8* __restrict__ mo) {
    const int N = 128 * SO * SO * SO;
    constexpr int SI = 2 * SO;
    int v = blockIdx.x * blockDim.x + threadIdx.x;
    if (v >= N) return;
    int t = v;
    int x = t % SO; t /= SO;
    int y = t % SO; t /= SO;
    int z = t % SO;
    int n = t / SO;
    u8 m = 0;
    for (int kd = 0; kd < 2; kd++)
        for (int kh = 0; kh < 2; kh++)
            for (int kw = 0; kw < 2; kw++)
                m |= mi[((n * SI + 2 * z + kd) * SI + 2 * y + kh) * SI + 2 * x + kw];
    mo[v] = m;
}

// ---------------- prepare conv 1->4, k=3, masked input+output, full batch ----------------
__global__ void prep_k(const float* __restrict__ vox, const u8* __restrict__ m,
                       const float* __restrict__ wp, float* __restrict__ out) {
    const int N = 128 * 32768;
    int v = blockIdx.x * blockDim.x + threadIdx.x;
    if (v >= N) return;
    if (!m[v]) {
#pragma unroll
        for (int co = 0; co < 4; co++) out[(size_t)v * 4 + co] = 0.f;
        return;
    }
    int t = v;
    int x = t & 31; t >>= 5;
    int y = t & 31; t >>= 5;
    int z = t & 31;
    int n = t >> 5;
    float p[4] = {0, 0, 0, 0};
    for (int kd = 0; kd < 3; kd++) {
        int zz = z + kd - 1; if ((unsigned)zz >= 32u) continue;
        for (int kh = 0; kh < 3; kh++) {
            int yy = y + kh - 1; if ((unsigned)yy >= 32u) continue;
            for (int kw = 0; kw < 3; kw++) {
                int xx = x + kw - 1; if ((unsigned)xx >= 32u) continue;
                int sv = ((n * 32 + zz) * 32 + yy) * 32 + xx;
                if (!m[sv]) continue;
                float xv = vox[sv];
                const float* w = wp + ((kd * 3 + kh) * 3 + kw) * 4;
#pragma unroll
                for (int co = 0; co < 4; co++) p[co] += xv * w[co];
            }
        }
    }
#pragma unroll
    for (int co = 0; co < 4; co++) out[(size_t)v * 4 + co] = p[co];
}

// ---------------- plain conv (input pre-masked/zeroed), k=3 pad(1,1) or k=4 pad(1,2) ----------------
template <int K, int CIN, int COUT, int S>
__global__ void conv_k(const float* __restrict__ in, const float* __restrict__ w,
                       const u8* __restrict__ outmask, float* __restrict__ out) {
    const int N = 128 * S * S * S;
    int v = blockIdx.x * blockDim.x + threadIdx.x;
    if (v >= N) return;
    if (!outmask[v]) {
#pragma unroll
        for (int co = 0; co < COUT; co++) out[(size_t)v * COUT + co] = 0.f;
        return;
    }
    int t = v;
    int x = t % S; t /= S;
    int y = t % S; t /= S;
    int z = t % S;
    int n = t / S;
    float acc[COUT];
#pragma unroll
    for (int co = 0; co < COUT; co++) acc[co] = 0.f;
    constexpr int PLO = (K - 1) / 2;
    for (int kd = 0; kd < K; kd++) {
        int zz = z + kd - PLO; if ((unsigned)zz >= (unsigned)S) continue;
        for (int kh = 0; kh < K; kh++) {
            int yy = y + kh - PLO; if ((unsigned)yy >= (unsigned)S) continue;
            for (int kw = 0; kw < K; kw++) {
                int xx = x + kw - PLO; if ((unsigned)xx >= (unsigned)S) continue;
                int sv = ((n * S + zz) * S + yy) * S + xx;
                const float* ip = in + (size_t)sv * CIN;
                const float* wpk = w + ((kd * K + kh) * K + kw) * CIN * COUT;
#pragma unroll
                for (int ci = 0; ci < CIN; ci++) {
                    float xv = ip[ci];
#pragma unroll
                    for (int co = 0; co < COUT; co++) acc[co] += xv * wpk[ci * COUT + co];
                }
            }
        }
    }
#pragma unroll
    for (int co = 0; co < COUT; co++) out[(size_t)v * COUT + co] = acc[co];
}

// ---------------- conv k=3 with BN(affine+ReLU+mask) applied to input on load, full batch ----------------
template <int CIN, int COUT, int S>
__global__ void convbn_k(const float* __restrict__ in, const float* __restrict__ w,
                         const u8* __restrict__ mask, const double* __restrict__ params,
                         float* __restrict__ out) {
    const int N = 128 * S * S * S;
    int v = blockIdx.x * blockDim.x + threadIdx.x;
    if (v >= N) return;
    if (!mask[v]) {
#pragma unroll
        for (int co = 0; co < COUT; co++) out[(size_t)v * COUT + co] = 0.f;
        return;
    }
    int t = v;
    int x = t % S; t /= S;
    int y = t % S; t /= S;
    int z = t % S;
    int n = t / S;
    float sc[CIN], sh[CIN];
#pragma unroll
    for (int c = 0; c < CIN; c++) { sc[c] = (float)params[c]; sh[c] = (float)params[CIN + c]; }
    float acc[COUT];
#pragma unroll
    for (int co = 0; co < COUT; co++) acc[co] = 0.f;
    for (int kd = 0; kd < 3; kd++) {
        int zz = z + kd - 1; if ((unsigned)zz >= (unsigned)S) continue;
        for (int kh = 0; kh < 3; kh++) {
            int yy = y + kh - 1; if ((unsigned)yy >= (unsigned)S) continue;
            for (int kw = 0; kw < 3; kw++) {
                int xx = x + kw - 1; if ((unsigned)xx >= (unsigned)S) continue;
                int sv = ((n * S + zz) * S + yy) * S + xx;
                if (!mask[sv]) continue;
                const float* ip = in + (size_t)sv * CIN;
                const float* wpk = w + ((kd * 3 + kh) * 3 + kw) * CIN * COUT;
#pragma unroll
                for (int ci = 0; ci < CIN; ci++) {
                    float yv = fmaxf(ip[ci] * sc[ci] + sh[ci], 0.f);
#pragma unroll
                    for (int co = 0; co < COUT; co++) acc[co] += yv * wpk[ci * COUT + co];
                }
            }
        }
    }
#pragma unroll
    for (int co = 0; co < COUT; co++) out[(size_t)v * COUT + co] = acc[co];
}

// ---------------- conv k=3 + fused sparsify; gate = parent (half-res) mask; writes new mask ----------------
// Gate channel 0 + asum accumulate in fp64 (identical ordering to verified R9-R11 gate);
// other channels fp32. Gate: active iff acc0 > -delta * sum|terms|.
template <int CIN, int COUT, int S>
__global__ void conv3s_k(const float* __restrict__ in, const float* __restrict__ w,
                         const u8* __restrict__ pmask, u8* __restrict__ nmask,
                         float* __restrict__ out, double delta) {
    const int N = 128 * S * S * S;
    constexpr int SP = S / 2;
    int v = blockIdx.x * blockDim.x + threadIdx.x;
    if (v >= N) return;
    int t = v;
    int x = t % S; t /= S;
    int y = t % S; t /= S;
    int z = t % S;
    int n = t / S;
    int pidx = ((n * SP + (z >> 1)) * SP + (y >> 1)) * SP + (x >> 1);
    if (!pmask[pidx]) {
        nmask[v] = 0;
#pragma unroll
        for (int co = 0; co < COUT; co++) out[(size_t)v * COUT + co] = 0.f;
        return;
    }
    double acc0 = 0.0, asum = 0.0;
    float acc[COUT];
#pragma unroll
    for (int co = 0; co < COUT; co++) acc[co] = 0.f;
    for (int kd = 0; kd < 3; kd++) {
        int zz = z + kd - 1; if ((unsigned)zz >= (unsigned)S) continue;
        for (int kh = 0; kh < 3; kh++) {
            int yy = y + kh - 1; if ((unsigned)yy >= (unsigned)S) continue;
            for (int kw = 0; kw < 3; kw++) {
                int xx = x + kw - 1; if ((unsigned)xx >= (unsigned)S) continue;
                int sv = ((n * S + zz) * S + yy) * S + xx;
                const float* ip = in + (size_t)sv * CIN;
                const float* wpk = w + ((kd * 3 + kh) * 3 + kw) * CIN * COUT;
#pragma unroll
                for (int ci = 0; ci < CIN; ci++) {
                    float xv = ip[ci];
                    double term = (double)xv * (double)wpk[ci * COUT + 0];
                    acc0 += term;
                    asum += fabs(term);
#pragma unroll
                    for (int co = 1; co < COUT; co++) acc[co] += xv * wpk[ci * COUT + co];
                }
            }
        }
    }
    u8 nm = (acc0 > -delta * asum) ? 1 : 0;
    nmask[v] = nm;
    out[(size_t)v * COUT + 0] = nm ? (float)acc0 : 0.f;
#pragma unroll
    for (int co = 1; co < COUT; co++) out[(size_t)v * COUT + co] = nm ? acc[co] : 0.f;
}

// ---------------- strided down conv k=2 s=2 (input pre-masked) ----------------
template <int CIN, int COUT, int SO>
__global__ void down_k(const float* __restrict__ in, const float* __restrict__ w,
                       const u8* __restrict__ outmask, float* __restrict__ out) {
    const int N = 128 * SO * SO * SO;
    constexpr int SI = 2 * SO;
    int v = blockIdx.x * blockDim.x + threadIdx.x;
    if (v >= N) return;
    if (!outmask[v]) {
#pragma unroll
        for (int co = 0; co < COUT; co++) out[(size_t)v * COUT + co] = 0.f;
        return;
    }
    int t = v;
    int x = t % SO; t /= SO;
    int y = t % SO; t /= SO;
    int z = t % SO;
    int n = t / SO;
    float acc[COUT];
#pragma unroll
    for (int co = 0; co < COUT; co++) acc[co] = 0.f;
    for (int kd = 0; kd < 2; kd++)
        for (int kh = 0; kh < 2; kh++)
            for (int kw = 0; kw < 2; kw++) {
                int sv = ((n * SI + 2 * z + kd) * SI + 2 * y + kh) * SI + 2 * x + kw;
                const float* ip = in + (size_t)sv * CIN;
                const float* wpk = w + ((kd * 2 + kh) * 2 + kw) * CIN * COUT;
#pragma unroll
                for (int ci = 0; ci < CIN; ci++) {
                    float xv = ip[ci];
#pragma unroll
                    for (int co = 0; co < COUT; co++) acc[co] += xv * wpk[ci * COUT + co];
                }
            }
#pragma unroll
    for (int co = 0; co < COUT; co++) out[(size_t)v * COUT + co] = acc[co];
}

// ---------------- fused BN + transposed conv k=2 s=2: out[2j+r] = relu(aff(x[j]))*w[1-r] ----------------
template <int CIN, int COUT, int SI>
__global__ void upbn_k(const float* __restrict__ in, const float* __restrict__ w,
                       const u8* __restrict__ inmask, const double* __restrict__ params,
                       float* __restrict__ out) {
    constexpr int SO = 2 * SI;
    const int N = 128 * SO * SO * SO;
    int v = blockIdx.x * blockDim.x + threadIdx.x;
    if (v >= N) return;
    int t = v;
    int x = t % SO; t /= SO;
    int y = t % SO; t /= SO;
    int z = t % SO;
    int n = t / SO;
    int sv = ((n * SI + (z >> 1)) * SI + (y >> 1)) * SI + (x >> 1);
    if (!inmask[sv]) {
#pragma unroll
        for (int co = 0; co < COUT; co++) out[(size_t)v * COUT + co] = 0.f;
        return;
    }
    int tap = ((1 - (z & 1)) * 2 + (1 - (y & 1))) * 2 + (1 - (x & 1));
    const float* wpk = w + tap * CIN * COUT;
    const float* ip = in + (size_t)sv * CIN;
    float acc[COUT];
#pragma unroll
    for (int co = 0; co < COUT; co++) acc[co] = 0.f;
#pragma unroll
    for (int ci = 0; ci < CIN; ci++) {
        float yv = fmaxf(ip[ci] * (float)params[ci] + (float)params[CIN + ci], 0.f);
#pragma unroll
        for (int co = 0; co < COUT; co++) acc[co] += yv * wpk[ci * COUT + co];
    }
#pragma unroll
    for (int co = 0; co < COUT; co++) out[(size_t)v * COUT + co] = acc[co];
}

// ---------------- BN masked reduce, DETERMINISTIC two-pass: per-block partials (no atomics) ----------------
template <int C>
__global__ void bn_reduce_k(const float* __restrict__ x, const u8* __restrict__ m, int N,
                            double* __restrict__ partial) {
    double cnt = 0.0, sx[C], s2[C];
#pragma unroll
    for (int c = 0; c < C; c++) { sx[c] = 0.0; s2[c] = 0.0; }
    int stride = gridDim.x * blockDim.x;
    for (int v = blockIdx.x * blockDim.x + threadIdx.x; v < N; v += stride) {
        if (!m[v]) continue;
        cnt += 1.0;
#pragma unroll
        for (int c = 0; c < C; c++) {
            double xv = (double)x[(size_t)v * C + c];
            sx[c] += xv;
            s2[c] += xv * xv;
        }
    }
#pragma unroll
    for (int off = 32; off > 0; off >>= 1) {
        cnt += __shfl_down(cnt, off, 64);
#pragma unroll
        for (int c = 0; c < C; c++) {
            sx[c] += __shfl_down(sx[c], off, 64);
            s2[c] += __shfl_down(s2[c], off, 64);
        }
    }
    __shared__ double sbuf[4][2 * C + 1];
    int wave = threadIdx.x >> 6;
    if ((threadIdx.x & 63) == 0) {
        sbuf[wave][0] = cnt;
#pragma unroll
        for (int c = 0; c < C; c++) {
            sbuf[wave][1 + c] = sx[c];
            sbuf[wave][1 + C + c] = s2[c];
        }
    }
    __syncthreads();
    if (threadIdx.x == 0) {
        double* p = partial + (size_t)blockIdx.x * (2 * C + 1);
        double tcnt = 0.0;
        for (int wv = 0; wv < 4; wv++) tcnt += sbuf[wv][0];
        p[0] = tcnt;
#pragma unroll
        for (int c = 0; c < C; c++) {
            double a = 0.0, b = 0.0;
            for (int wv = 0; wv < 4; wv++) { a += sbuf[wv][1 + c]; b += sbuf[wv][1 + C + c]; }
            p[1 + c] = a;
            p[1 + C + c] = b;
        }
    }
}

// ---------------- BN finalize: fixed-order sum of block partials, then scale/shift ----------------
template <int C>
__global__ void bn_final_k(const double* __restrict__ partial, int nblocks,
                           const float* __restrict__ g, const float* __restrict__ b,
                           double* __restrict__ params) {
    int c = threadIdx.x;
    if (c >= C) return;
    double cnt = 0.0, sx = 0.0, s2 = 0.0;
    for (int bk = 0; bk < nblocks; bk++) {
        const double* p = partial + (size_t)bk * (2 * C + 1);
        cnt += p[0];
        sx += p[1 + c];
        s2 += p[1 + C + c];
    }
    if (cnt < 1.0) cnt = 1.0;
    double mean = sx / cnt;
    double var = s2 / cnt - mean * mean;
    double sc = (double)g[c] / sqrt(var + 1e-4);
    params[c] = sc;
    params[C + c] = (double)b[c] - mean * sc;
}

// ---------------- final output conv k=3, 4->1, full batch, fp32 out ----------------
__global__ void outconv_k(const float* __restrict__ in, const float* __restrict__ w,
                          const u8* __restrict__ mask, float* __restrict__ out) {
    const int N = 128 * 32768;
    int v = blockIdx.x * blockDim.x + threadIdx.x;
    if (v >= N) return;
    if (!mask[v]) { out[v] = 0.f; return; }
    int t = v;
    int x = t & 31; t >>= 5;
    int y = t & 31; t >>= 5;
    int z = t & 31;
    int n = t >> 5;
    float acc = 0.f;
    for (int kd = 0; kd < 3; kd++) {
        int zz = z + kd - 1; if ((unsigned)zz >= 32u) continue;
        for (int kh = 0; kh < 3; kh++) {
            int yy = y + kh - 1; if ((unsigned)yy >= 32u) continue;
            for (int kw = 0; kw < 3; kw++) {
                int xx = x + kw - 1; if ((unsigned)xx >= 32u) continue;
                int sv = ((n * 32 + zz) * 32 + yy) * 32 + xx;
                const float* ip = in + (size_t)sv * 4;
                const float* wpk = w + ((kd * 3 + kh) * 3 + kw) * 4;
#pragma unroll
                for (int ci = 0; ci < 4; ci++) acc += ip[ci] * wpk[ci];
            }
        }
    }
    out[v] = acc;
}

// ---------------- hidden: NDHWC (4^3, 32ch) -> NCDHW flat ----------------
__global__ void hidden_k(const float* __restrict__ x, float* __restrict__ out) {
    int i = blockIdx.x * blockDim.x + threadIdx.x;
    if (i >= 128 * 2048) return;
    int b = i >> 11;
    int r = i & 2047;
    int c = r >> 6;
    int s = r & 63;
    int d = s >> 4;
    int h = (s >> 2) & 3;
    int w = s & 3;
    out[i] = x[((((b * 4 + d) * 4 + h) * 4 + w) << 5) + c];
}

extern "C" void kernel_launch(void* const* d_in, const int* in_sizes, int n_in,
                              void* d_out, int out_size, void* d_ws, size_t ws_size,
                              hipStream_t stream) {
    const float* vox = (const float*)d_in[0];
    const int* mraw = (const int*)d_in[1];
    const float* wp = (const float*)d_in[2];
    const float* g_e0 = (const float*)d_in[3];
    const float* b_e0 = (const float*)d_in[4];
    const float* ws_e0 = (const float*)d_in[5];
    const float* wd_e0 = (const float*)d_in[6];
    const float* g_e1 = (const float*)d_in[7];
    const float* b_e1 = (const float*)d_in[8];
    const float* ws_e1 = (const float*)d_in[9];
    const float* wd_e1 = (const float*)d_in[10];
    const float* g_e2 = (const float*)d_in[11];
    const float* b_e2 = (const float*)d_in[12];
    const float* ws_e2 = (const float*)d_in[13];
    const float* wd_e2 = (const float*)d_in[14];
    const float* g_d0 = (const float*)d_in[15];
    const float* b_d0 = (const float*)d_in[16];
    const float* wu_d0 = (const float*)d_in[17];
    const float* ws3_d0 = (const float*)d_in[18];
    const float* ws4_d0 = (const float*)d_in[19];
    const float* g_d1 = (const float*)d_in[20];
    const float* b_d1 = (const float*)d_in[21];
    const float* wu_d1 = (const float*)d_in[22];
    const float* ws3_d1 = (const float*)d_in[23];
    const float* ws4_d1 = (const float*)d_in[24];
    const float* g_d2 = (const float*)d_in[25];
    const float* b_d2 = (const float*)d_in[26];
    const float* wu_d2 = (const float*)d_in[27];
    const float* ws3_d2 = (const float*)d_in[28];
    const float* ws4_d2 = (const float*)d_in[29];
    const float* wo = (const float*)d_in[30];
    float* out = (float*)d_out;

    // ---- workspace: fp32 tensors + fp64 partials/params + u8 masks (~153 MB) ----
    float* wsf = (float*)d_ws;
    size_t offf = 0;
    auto allocf = [&](size_t n) { float* p = wsf + offf; offf += n; return p; };
    float* R1 = allocf(16777216);  // 128*32^3*4ch fp32 (head aliases 16^3*8ch)
    float* R2 = allocf(16777216);
    float* S1 = allocf(1048576);   // 128*8^3*16ch
    float* S2 = allocf(1048576);
    float* T = allocf(262144);     // 128*4^3*32ch
    double* wsd = (double*)(wsf + offf);
    double* partial = wsd;          // up to 256 blocks x (2*32+1) doubles = 16640
    double* params = wsd + 16640;
    u8* wsm = (u8*)(wsd + 16640 + 128);
    size_t offm = 0;
    auto allocm = [&](size_t n) { u8* p = wsm + offm; offm += n; return p; };
    u8* m32 = allocm(4194304);
    u8* m16 = allocm(524288);
    u8* m8 = allocm(65536);
    u8* m4 = allocm(8192);
    u8* mD8 = allocm(65536);
    u8* mD16 = allocm(524288);
    u8* mD32 = allocm(4194304);

    const int N32 = 128 * 32768;
    const int N16 = 128 * 4096;
    const int N8 = 128 * 512;
    const int N4 = 128 * 64;
    auto gs = [](int n) { return dim3((n + 255) / 256); };
    auto rbn = [](int n) { int bl = (n + 255) / 256; return bl > 256 ? 256 : bl; };
    dim3 blk(256);

    // masks
    mask_init_k<<<gs(N32), blk, 0, stream>>>(mraw, m32, N32);
    pool_k<16><<<gs(N16), blk, 0, stream>>>(m32, m16);
    pool_k<8><<<gs(N8), blk, 0, stream>>>(m16, m8);
    pool_k<4><<<gs(N4), blk, 0, stream>>>(m8, m4);

    // ---- encoder stage 0 @32^3, full batch ----
    prep_k<<<gs(N32), blk, 0, stream>>>(vox, m32, wp, R1);
    int nb0 = rbn(N32);
    bn_reduce_k<4><<<dim3(nb0), blk, 0, stream>>>(R1, m32, N32, partial);
    bn_final_k<4><<<1, 64, 0, stream>>>(partial, nb0, g_e0, b_e0, params);
    convbn_k<4, 4, 32><<<gs(N32), blk, 0, stream>>>(R1, ws_e0, m32, params, R2);
    down_k<4, 8, 16><<<gs(N16), blk, 0, stream>>>(R2, wd_e0, m16, R1);

    // ---- encoder stage 1 @16^3 ----
    int nb1 = rbn(N16);
    bn_reduce_k<8><<<dim3(nb1), blk, 0, stream>>>(R1, m16, N16, partial);
    bn_final_k<8><<<1, 64, 0, stream>>>(partial, nb1, g_e1, b_e1, params);
    convbn_k<8, 8, 16><<<gs(N16), blk, 0, stream>>>(R1, ws_e1, m16, params, R2);
    down_k<8, 16, 8><<<gs(N8), blk, 0, stream>>>(R2, wd_e1, m8, S1);

    // ---- encoder stage 2 @8^3 ----
    int nb2 = rbn(N8);
    bn_reduce_k<16><<<dim3(nb2), blk, 0, stream>>>(S1, m8, N8, partial);
    bn_final_k<16><<<1, 64, 0, stream>>>(partial, nb2, g_e2, b_e2, params);
    convbn_k<16, 16, 8><<<gs(N8), blk, 0, stream>>>(S1, ws_e2, m8, params, S2);
    down_k<16, 32, 4><<<gs(N4), blk, 0, stream>>>(S2, wd_e2, m4, T);

    // ---- hidden ----
    hidden_k<<<gs(128 * 2048), blk, 0, stream>>>(T, out);

    // ---- decoder stage 0 (32->16, 4^3 -> 8^3), band gate delta=4e-7 ----
    int nb3 = rbn(N4);
    bn_reduce_k<32><<<dim3(nb3), blk, 0, stream>>>(T, m4, N4, partial);
    bn_final_k<32><<<1, 64, 0, stream>>>(partial, nb3, g_d0, b_d0, params);
    upbn_k<32, 16, 4><<<gs(N8), blk, 0, stream>>>(T, wu_d0, m4, params, S1);
    conv3s_k<16, 16, 8><<<gs(N8), blk, 0, stream>>>(S1, ws3_d0, m4, mD8, S2, 4e-7);
    conv_k<4, 16, 16, 8><<<gs(N8), blk, 0, stream>>>(S2, ws4_d0, mD8, S1);

    // ---- decoder stage 1 (16->8, 8^3 -> 16^3), band gate delta=4e-7 ----
    int nb4 = rbn(N8);
    bn_reduce_k<16><<<dim3(nb4), blk, 0, stream>>>(S1, mD8, N8, partial);
    bn_final_k<16><<<1, 64, 0, stream>>>(partial, nb4, g_d1, b_d1, params);
    upbn_k<16, 8, 8><<<gs(N16), blk, 0, stream>>>(S1, wu_d1, mD8, params, R1);
    conv3s_k<8, 8, 16><<<gs(N16), blk, 0, stream>>>(R1, ws3_d1, mD8, mD16, R2, 4e-7);
    conv_k<4, 8, 8, 16><<<gs(N16), blk, 0, stream>>>(R2, ws4_d1, mD16, R1);

    // ---- decoder stage 2 (8->4, 16^3 -> 32^3), exact gate ----
    int nb5 = rbn(N16);
    bn_reduce_k<8><<<dim3(nb5), blk, 0, stream>>>(R1, mD16, N16, partial);
    bn_final_k<8><<<1, 64, 0, stream>>>(partial, nb5, g_d2, b_d2, params);
    upbn_k<8, 4, 16><<<gs(N32), blk, 0, stream>>>(R1, wu_d2, mD16, params, R2);
    conv3s_k<4, 4, 32><<<gs(N32), blk, 0, stream>>>(R2, ws3_d2, mD16, mD32, R1, 0.0);
    conv_k<4, 4, 4, 32><<<gs(N32), blk, 0, stream>>>(R1, ws4_d2, mD32, R2);
    outconv_k<<<gs(N32), blk, 0, stream>>>(R2, wo, mD32, out + 262144);
}

// Round 14
// 1754.475 us; speedup vs baseline: 2.7528x; 1.0072x over previous
//
#include <hip/hip_runtime.h>

using u8 = unsigned char;

// ---------------- mask init: m = (maskraw == 0) ----------------
__global__ void mask_init_k(const int* __restrict__ mr, u8* __restrict__ m, int N) {
    int i = blockIdx.x * blockDim.x + threadIdx.x;
    if (i < N) m[i] = (mr[i] == 0) ? 1 : 0;
}

// ---------------- mask pool 2x2x2 (logical OR), full batch ----------------
template <int SO>
__global__ void pool_k(const u8* __restrict__ mi, u8* __restrict__ mo) {
    const int N = 128 * SO * SO * SO;
    constexpr int SI = 2 * SO;
    int v = blockIdx.x * blockDim.x + threadIdx.x;
    if (v >= N) return;
    int t = v;
    int x = t % SO; t /= SO;
    int y = t % SO; t /= SO;
    int z = t % SO;
    int n = t / SO;
    u8 m = 0;
    for (int kd = 0; kd < 2; kd++)
        for (int kh = 0; kh < 2; kh++)
            for (int kw = 0; kw < 2; kw++)
                m |= mi[((n * SI + 2 * z + kd) * SI + 2 * y + kh) * SI + 2 * x + kw];
    mo[v] = m;
}

// ================= 32^3 XPT=4 kernels: each thread computes 4 consecutive-x voxels =================
// group decode: g = v>>2;  xb=(g&7)*4, y=(g>>3)&31, z=(g>>8)&31, n=g>>13, vbase=((g>>3)<<5)+xb

// ---------------- prepare conv 1->4, k=3, masked input+output ----------------
__global__ void prep4_k(const float* __restrict__ vox, const u8* __restrict__ m,
                        const float* __restrict__ wp, float* __restrict__ out) {
    const int NG = 128 * 32768 / 4;
    int g = blockIdx.x * blockDim.x + threadIdx.x;
    if (g >= NG) return;
    int xb = (g & 7) << 2;
    int y = (g >> 3) & 31;
    int z = (g >> 8) & 31;
    int n = g >> 13;
    int vbase = ((g >> 3) << 5) + xb;
    u8 om[4];
#pragma unroll
    for (int j = 0; j < 4; j++) om[j] = m[vbase + j];
    if (!(om[0] | om[1] | om[2] | om[3])) {
#pragma unroll
        for (int j = 0; j < 4; j++)
#pragma unroll
            for (int co = 0; co < 4; co++) out[(size_t)(vbase + j) * 4 + co] = 0.f;
        return;
    }
    float acc[4][4];
#pragma unroll
    for (int j = 0; j < 4; j++)
#pragma unroll
        for (int co = 0; co < 4; co++) acc[j][co] = 0.f;
    for (int kd = 0; kd < 3; kd++) {
        int zz = z + kd - 1; if ((unsigned)zz >= 32u) continue;
        for (int kh = 0; kh < 3; kh++) {
            int yy = y + kh - 1; if ((unsigned)yy >= 32u) continue;
            int base = ((n * 32 + zz) * 32 + yy) * 32;
            float col[6];
#pragma unroll
            for (int c = 0; c < 6; c++) {
                int xx = xb - 1 + c;
                col[c] = ((unsigned)xx < 32u && m[base + xx]) ? vox[base + xx] : 0.f;
            }
            const float* wrow = wp + ((kd * 3 + kh) * 3) * 4;
#pragma unroll
            for (int kw = 0; kw < 3; kw++) {
                const float* wt = wrow + kw * 4;
#pragma unroll
                for (int j = 0; j < 4; j++) {
                    float xv = col[j + kw];
#pragma unroll
                    for (int co = 0; co < 4; co++) acc[j][co] += xv * wt[co];
                }
            }
        }
    }
#pragma unroll
    for (int j = 0; j < 4; j++)
#pragma unroll
        for (int co = 0; co < 4; co++)
            out[(size_t)(vbase + j) * 4 + co] = om[j] ? acc[j][co] : 0.f;
}

// ---------------- conv k=3, 4->4, BN(affine+ReLU+mask) on load, mask-gated output ----------------
__global__ void convbn4_k(const float* __restrict__ in, const float* __restrict__ w,
                          const u8* __restrict__ mask, const double* __restrict__ params,
                          float* __restrict__ out) {
    const int NG = 128 * 32768 / 4;
    int g = blockIdx.x * blockDim.x + threadIdx.x;
    if (g >= NG) return;
    int xb = (g & 7) << 2;
    int y = (g >> 3) & 31;
    int z = (g >> 8) & 31;
    int n = g >> 13;
    int vbase = ((g >> 3) << 5) + xb;
    u8 om[4];
#pragma unroll
    for (int j = 0; j < 4; j++) om[j] = mask[vbase + j];
    if (!(om[0] | om[1] | om[2] | om[3])) {
#pragma unroll
        for (int j = 0; j < 4; j++)
#pragma unroll
            for (int co = 0; co < 4; co++) out[(size_t)(vbase + j) * 4 + co] = 0.f;
        return;
    }
    float sc[4], sh[4];
#pragma unroll
    for (int c = 0; c < 4; c++) { sc[c] = (float)params[c]; sh[c] = (float)params[4 + c]; }
    float acc[4][4];
#pragma unroll
    for (int j = 0; j < 4; j++)
#pragma unroll
        for (int co = 0; co < 4; co++) acc[j][co] = 0.f;
    for (int kd = 0; kd < 3; kd++) {
        int zz = z + kd - 1; if ((unsigned)zz >= 32u) continue;
        for (int kh = 0; kh < 3; kh++) {
            int yy = y + kh - 1; if ((unsigned)yy >= 32u) continue;
            int base = ((n * 32 + zz) * 32 + yy) * 32;
            float col[6][4];
#pragma unroll
            for (int c = 0; c < 6; c++) {
                int xx = xb - 1 + c;
                bool valid = ((unsigned)xx < 32u) && mask[base + xx];
                const float* ip = in + (size_t)(base + xx) * 4;
#pragma unroll
                for (int ci = 0; ci < 4; ci++)
                    col[c][ci] = valid ? fmaxf(ip[ci] * sc[ci] + sh[ci], 0.f) : 0.f;
            }
            const float* wrow = w + ((kd * 3 + kh) * 3) * 16;
#pragma unroll
            for (int kw = 0; kw < 3; kw++) {
                const float* wt = wrow + kw * 16;
#pragma unroll
                for (int j = 0; j < 4; j++) {
#pragma unroll
                    for (int ci = 0; ci < 4; ci++) {
                        float xv = col[j + kw][ci];
#pragma unroll
                        for (int co = 0; co < 4; co++) acc[j][co] += xv * wt[ci * 4 + co];
                    }
                }
            }
        }
    }
#pragma unroll
    for (int j = 0; j < 4; j++)
#pragma unroll
        for (int co = 0; co < 4; co++)
            out[(size_t)(vbase + j) * 4 + co] = om[j] ? acc[j][co] : 0.f;
}

// ---------------- plain conv 4->4, k=3 pad(1,1) or k=4 pad(1,2), mask-gated output ----------------
template <int K>
__global__ void conv4x4_k(const float* __restrict__ in, const float* __restrict__ w,
                          const u8* __restrict__ outmask, float* __restrict__ out) {
    const int NG = 128 * 32768 / 4;
    constexpr int PLO = (K - 1) / 2;
    constexpr int NC = K + 3;
    int g = blockIdx.x * blockDim.x + threadIdx.x;
    if (g >= NG) return;
    int xb = (g & 7) << 2;
    int y = (g >> 3) & 31;
    int z = (g >> 8) & 31;
    int n = g >> 13;
    int vbase = ((g >> 3) << 5) + xb;
    u8 om[4];
#pragma unroll
    for (int j = 0; j < 4; j++) om[j] = outmask[vbase + j];
    if (!(om[0] | om[1] | om[2] | om[3])) {
#pragma unroll
        for (int j = 0; j < 4; j++)
#pragma unroll
            for (int co = 0; co < 4; co++) out[(size_t)(vbase + j) * 4 + co] = 0.f;
        return;
    }
    float acc[4][4];
#pragma unroll
    for (int j = 0; j < 4; j++)
#pragma unroll
        for (int co = 0; co < 4; co++) acc[j][co] = 0.f;
    for (int kd = 0; kd < K; kd++) {
        int zz = z + kd - PLO; if ((unsigned)zz >= 32u) continue;
        for (int kh = 0; kh < K; kh++) {
            int yy = y + kh - PLO; if ((unsigned)yy >= 32u) continue;
            int base = ((n * 32 + zz) * 32 + yy) * 32;
            float col[NC][4];
#pragma unroll
            for (int c = 0; c < NC; c++) {
                int xx = xb - PLO + c;
                bool valid = ((unsigned)xx < 32u);
                const float* ip = in + (size_t)(base + xx) * 4;
#pragma unroll
                for (int ci = 0; ci < 4; ci++) col[c][ci] = valid ? ip[ci] : 0.f;
            }
            const float* wrow = w + ((kd * K + kh) * K) * 16;
#pragma unroll
            for (int kw = 0; kw < K; kw++) {
                const float* wt = wrow + kw * 16;
#pragma unroll
                for (int j = 0; j < 4; j++) {
#pragma unroll
                    for (int ci = 0; ci < 4; ci++) {
                        float xv = col[j + kw][ci];
#pragma unroll
                        for (int co = 0; co < 4; co++) acc[j][co] += xv * wt[ci * 4 + co];
                    }
                }
            }
        }
    }
#pragma unroll
    for (int j = 0; j < 4; j++)
#pragma unroll
        for (int co = 0; co < 4; co++)
            out[(size_t)(vbase + j) * 4 + co] = om[j] ? acc[j][co] : 0.f;
}

// ---------------- conv k=3 4->4 + fused sparsify (fp64 gate, order-preserving) ----------------
__global__ void conv3s4_k(const float* __restrict__ in, const float* __restrict__ w,
                          const u8* __restrict__ pmask, u8* __restrict__ nmask,
                          float* __restrict__ out, double delta) {
    const int NG = 128 * 32768 / 4;
    int g = blockIdx.x * blockDim.x + threadIdx.x;
    if (g >= NG) return;
    int xb = (g & 7) << 2;
    int y = (g >> 3) & 31;
    int z = (g >> 8) & 31;
    int n = g >> 13;
    int vbase = ((g >> 3) << 5) + xb;
    int pbase = ((n * 16 + (z >> 1)) * 16 + (y >> 1)) * 16 + (xb >> 1);
    u8 pm[4];
    pm[0] = pm[1] = pmask[pbase];
    pm[2] = pm[3] = pmask[pbase + 1];
    if (!(pm[0] | pm[2])) {
#pragma unroll
        for (int j = 0; j < 4; j++) {
            nmask[vbase + j] = 0;
#pragma unroll
            for (int co = 0; co < 4; co++) out[(size_t)(vbase + j) * 4 + co] = 0.f;
        }
        return;
    }
    double acc0[4], asum[4];
    float accf[4][4];
#pragma unroll
    for (int j = 0; j < 4; j++) {
        acc0[j] = 0.0; asum[j] = 0.0;
#pragma unroll
        for (int co = 0; co < 4; co++) accf[j][co] = 0.f;
    }
    for (int kd = 0; kd < 3; kd++) {
        int zz = z + kd - 1; if ((unsigned)zz >= 32u) continue;
        for (int kh = 0; kh < 3; kh++) {
            int yy = y + kh - 1; if ((unsigned)yy >= 32u) continue;
            int base = ((n * 32 + zz) * 32 + yy) * 32;
            float col[6][4];
#pragma unroll
            for (int c = 0; c < 6; c++) {
                int xx = xb - 1 + c;
                bool valid = ((unsigned)xx < 32u);
                const float* ip = in + (size_t)(base + xx) * 4;
#pragma unroll
                for (int ci = 0; ci < 4; ci++) col[c][ci] = valid ? ip[ci] : 0.f;
            }
            const float* wrow = w + ((kd * 3 + kh) * 3) * 16;
#pragma unroll
            for (int kw = 0; kw < 3; kw++) {
                const float* wt = wrow + kw * 16;
#pragma unroll
                for (int j = 0; j < 4; j++) {
#pragma unroll
                    for (int ci = 0; ci < 4; ci++) {
                        float xv = col[j + kw][ci];
                        double term = (double)xv * (double)wt[ci * 4 + 0];
                        acc0[j] += term;
                        asum[j] += fabs(term);
#pragma unroll
                        for (int co = 1; co < 4; co++) accf[j][co] += xv * wt[ci * 4 + co];
                    }
                }
            }
        }
    }
#pragma unroll
    for (int j = 0; j < 4; j++) {
        u8 nm = (pm[j] && (acc0[j] > -delta * asum[j])) ? 1 : 0;
        nmask[vbase + j] = nm;
        out[(size_t)(vbase + j) * 4 + 0] = nm ? (float)acc0[j] : 0.f;
#pragma unroll
        for (int co = 1; co < 4; co++) out[(size_t)(vbase + j) * 4 + co] = nm ? accf[j][co] : 0.f;
    }
}

// ---------------- final output conv k=3, 4->1, mask-gated ----------------
__global__ void outconv4_k(const float* __restrict__ in, const float* __restrict__ w,
                           const u8* __restrict__ mask, float* __restrict__ out) {
    const int NG = 128 * 32768 / 4;
    int g = blockIdx.x * blockDim.x + threadIdx.x;
    if (g >= NG) return;
    int xb = (g & 7) << 2;
    int y = (g >> 3) & 31;
    int z = (g >> 8) & 31;
    int n = g >> 13;
    int vbase = ((g >> 3) << 5) + xb;
    u8 om[4];
#pragma unroll
    for (int j = 0; j < 4; j++) om[j] = mask[vbase + j];
    if (!(om[0] | om[1] | om[2] | om[3])) {
#pragma unroll
        for (int j = 0; j < 4; j++) out[vbase + j] = 0.f;
        return;
    }
    float acc[4] = {0.f, 0.f, 0.f, 0.f};
    for (int kd = 0; kd < 3; kd++) {
        int zz = z + kd - 1; if ((unsigned)zz >= 32u) continue;
        for (int kh = 0; kh < 3; kh++) {
            int yy = y + kh - 1; if ((unsigned)yy >= 32u) continue;
            int base = ((n * 32 + zz) * 32 + yy) * 32;
            float col[6][4];
#pragma unroll
            for (int c = 0; c < 6; c++) {
                int xx = xb - 1 + c;
                bool valid = ((unsigned)xx < 32u);
                const float* ip = in + (size_t)(base + xx) * 4;
#pragma unroll
                for (int ci = 0; ci < 4; ci++) col[c][ci] = valid ? ip[ci] : 0.f;
            }
            const float* wrow = w + ((kd * 3 + kh) * 3) * 4;
#pragma unroll
            for (int kw = 0; kw < 3; kw++) {
                const float* wt = wrow + kw * 4;
#pragma unroll
                for (int j = 0; j < 4; j++) {
#pragma unroll
                    for (int ci = 0; ci < 4; ci++) acc[j] += col[j + kw][ci] * wt[ci];
                }
            }
        }
    }
#pragma unroll
    for (int j = 0; j < 4; j++) out[vbase + j] = om[j] ? acc[j] : 0.f;
}

// ================= generic kernels for 16^3 / 8^3 stages (unchanged from R13) =================

template <int K, int CIN, int COUT, int S>
__global__ void conv_k(const float* __restrict__ in, const float* __restrict__ w,
                       const u8* __restrict__ outmask, float* __restrict__ out) {
    const int N = 128 * S * S * S;
    int v = blockIdx.x * blockDim.x + threadIdx.x;
    if (v >= N) return;
    if (!outmask[v]) {
#pragma unroll
        for (int co = 0; co < COUT; co++) out[(size_t)v * COUT + co] = 0.f;
        return;
    }
    int t = v;
    int x = t % S; t /= S;
    int y = t % S; t /= S;
    int z = t % S;
    int n = t / S;
    float acc[COUT];
#pragma unroll
    for (int co = 0; co < COUT; co++) acc[co] = 0.f;
    constexpr int PLO = (K - 1) / 2;
    for (int kd = 0; kd < K; kd++) {
        int zz = z + kd - PLO; if ((unsigned)zz >= (unsigned)S) continue;
        for (int kh = 0; kh < K; kh++) {
            int yy = y + kh - PLO; if ((unsigned)yy >= (unsigned)S) continue;
            for (int kw = 0; kw < K; kw++) {
                int xx = x + kw - PLO; if ((unsigned)xx >= (unsigned)S) continue;
                int sv = ((n * S + zz) * S + yy) * S + xx;
                const float* ip = in + (size_t)sv * CIN;
                const float* wpk = w + ((kd * K + kh) * K + kw) * CIN * COUT;
#pragma unroll
                for (int ci = 0; ci < CIN; ci++) {
                    float xv = ip[ci];
#pragma unroll
                    for (int co = 0; co < COUT; co++) acc[co] += xv * wpk[ci * COUT + co];
                }
            }
        }
    }
#pragma unroll
    for (int co = 0; co < COUT; co++) out[(size_t)v * COUT + co] = acc[co];
}

template <int CIN, int COUT, int S>
__global__ void convbn_k(const float* __restrict__ in, const float* __restrict__ w,
                         const u8* __restrict__ mask, const double* __restrict__ params,
                         float* __restrict__ out) {
    const int N = 128 * S * S * S;
    int v = blockIdx.x * blockDim.x + threadIdx.x;
    if (v >= N) return;
    if (!mask[v]) {
#pragma unroll
        for (int co = 0; co < COUT; co++) out[(size_t)v * COUT + co] = 0.f;
        return;
    }
    int t = v;
    int x = t % S; t /= S;
    int y = t % S; t /= S;
    int z = t % S;
    int n = t / S;
    float sc[CIN], sh[CIN];
#pragma unroll
    for (int c = 0; c < CIN; c++) { sc[c] = (float)params[c]; sh[c] = (float)params[CIN + c]; }
    float acc[COUT];
#pragma unroll
    for (int co = 0; co < COUT; co++) acc[co] = 0.f;
    for (int kd = 0; kd < 3; kd++) {
        int zz = z + kd - 1; if ((unsigned)zz >= (unsigned)S) continue;
        for (int kh = 0; kh < 3; kh++) {
            int yy = y + kh - 1; if ((unsigned)yy >= (unsigned)S) continue;
            for (int kw = 0; kw < 3; kw++) {
                int xx = x + kw - 1; if ((unsigned)xx >= (unsigned)S) continue;
                int sv = ((n * S + zz) * S + yy) * S + xx;
                if (!mask[sv]) continue;
                const float* ip = in + (size_t)sv * CIN;
                const float* wpk = w + ((kd * 3 + kh) * 3 + kw) * CIN * COUT;
#pragma unroll
                for (int ci = 0; ci < CIN; ci++) {
                    float yv = fmaxf(ip[ci] * sc[ci] + sh[ci], 0.f);
#pragma unroll
                    for (int co = 0; co < COUT; co++) acc[co] += yv * wpk[ci * COUT + co];
                }
            }
        }
    }
#pragma unroll
    for (int co = 0; co < COUT; co++) out[(size_t)v * COUT + co] = acc[co];
}

template <int CIN, int COUT, int S>
__global__ void conv3s_k(const float* __restrict__ in, const float* __restrict__ w,
                         const u8* __restrict__ pmask, u8* __restrict__ nmask,
                         float* __restrict__ out, double delta) {
    const int N = 128 * S * S * S;
    constexpr int SP = S / 2;
    int v = blockIdx.x * blockDim.x + threadIdx.x;
    if (v >= N) return;
    int t = v;
    int x = t % S; t /= S;
    int y = t % S; t /= S;
    int z = t % S;
    int n = t / S;
    int pidx = ((n * SP + (z >> 1)) * SP + (y >> 1)) * SP + (x >> 1);
    if (!pmask[pidx]) {
        nmask[v] = 0;
#pragma unroll
        for (int co = 0; co < COUT; co++) out[(size_t)v * COUT + co] = 0.f;
        return;
    }
    double acc0 = 0.0, asum = 0.0;
    float acc[COUT];
#pragma unroll
    for (int co = 0; co < COUT; co++) acc[co] = 0.f;
    for (int kd = 0; kd < 3; kd++) {
        int zz = z + kd - 1; if ((unsigned)zz >= (unsigned)S) continue;
        for (int kh = 0; kh < 3; kh++) {
            int yy = y + kh - 1; if ((unsigned)yy >= (unsigned)S) continue;
            for (int kw = 0; kw < 3; kw++) {
                int xx = x + kw - 1; if ((unsigned)xx >= (unsigned)S) continue;
                int sv = ((n * S + zz) * S + yy) * S + xx;
                const float* ip = in + (size_t)sv * CIN;
                const float* wpk = w + ((kd * 3 + kh) * 3 + kw) * CIN * COUT;
#pragma unroll
                for (int ci = 0; ci < CIN; ci++) {
                    float xv = ip[ci];
                    double term = (double)xv * (double)wpk[ci * COUT + 0];
                    acc0 += term;
                    asum += fabs(term);
#pragma unroll
                    for (int co = 1; co < COUT; co++) acc[co] += xv * wpk[ci * COUT + co];
                }
            }
        }
    }
    u8 nm = (acc0 > -delta * asum) ? 1 : 0;
    nmask[v] = nm;
    out[(size_t)v * COUT + 0] = nm ? (float)acc0 : 0.f;
#pragma unroll
    for (int co = 1; co < COUT; co++) out[(size_t)v * COUT + co] = nm ? acc[co] : 0.f;
}

template <int CIN, int COUT, int SO>
__global__ void down_k(const float* __restrict__ in, const float* __restrict__ w,
                       const u8* __restrict__ outmask, float* __restrict__ out) {
    const int N = 128 * SO * SO * SO;
    constexpr int SI = 2 * SO;
    int v = blockIdx.x * blockDim.x + threadIdx.x;
    if (v >= N) return;
    if (!outmask[v]) {
#pragma unroll
        for (int co = 0; co < COUT; co++) out[(size_t)v * COUT + co] = 0.f;
        return;
    }
    int t = v;
    int x = t % SO; t /= SO;
    int y = t % SO; t /= SO;
    int z = t % SO;
    int n = t / SO;
    float acc[COUT];
#pragma unroll
    for (int co = 0; co < COUT; co++) acc[co] = 0.f;
    for (int kd = 0; kd < 2; kd++)
        for (int kh = 0; kh < 2; kh++)
            for (int kw = 0; kw < 2; kw++) {
                int sv = ((n * SI + 2 * z + kd) * SI + 2 * y + kh) * SI + 2 * x + kw;
                const float* ip = in + (size_t)sv * CIN;
                const float* wpk = w + ((kd * 2 + kh) * 2 + kw) * CIN * COUT;
#pragma unroll
                for (int ci = 0; ci < CIN; ci++) {
                    float xv = ip[ci];
#pragma unroll
                    for (int co = 0; co < COUT; co++) acc[co] += xv * wpk[ci * COUT + co];
                }
            }
#pragma unroll
    for (int co = 0; co < COUT; co++) out[(size_t)v * COUT + co] = acc[co];
}

template <int CIN, int COUT, int SI>
__global__ void upbn_k(const float* __restrict__ in, const float* __restrict__ w,
                       const u8* __restrict__ inmask, const double* __restrict__ params,
                       float* __restrict__ out) {
    constexpr int SO = 2 * SI;
    const int N = 128 * SO * SO * SO;
    int v = blockIdx.x * blockDim.x + threadIdx.x;
    if (v >= N) return;
    int t = v;
    int x = t % SO; t /= SO;
    int y = t % SO; t /= SO;
    int z = t % SO;
    int n = t / SO;
    int sv = ((n * SI + (z >> 1)) * SI + (y >> 1)) * SI + (x >> 1);
    if (!inmask[sv]) {
#pragma unroll
        for (int co = 0; co < COUT; co++) out[(size_t)v * COUT + co] = 0.f;
        return;
    }
    int tap = ((1 - (z & 1)) * 2 + (1 - (y & 1))) * 2 + (1 - (x & 1));
    const float* wpk = w + tap * CIN * COUT;
    const float* ip = in + (size_t)sv * CIN;
    float acc[COUT];
#pragma unroll
    for (int co = 0; co < COUT; co++) acc[co] = 0.f;
#pragma unroll
    for (int ci = 0; ci < CIN; ci++) {
        float yv = fmaxf(ip[ci] * (float)params[ci] + (float)params[CIN + ci], 0.f);
#pragma unroll
        for (int co = 0; co < COUT; co++) acc[co] += yv * wpk[ci * COUT + co];
    }
#pragma unroll
    for (int co = 0; co < COUT; co++) out[(size_t)v * COUT + co] = acc[co];
}

// ---------------- BN masked reduce, DETERMINISTIC two-pass: per-block partials ----------------
template <int C>
__global__ void bn_reduce_k(const float* __restrict__ x, const u8* __restrict__ m, int N,
                            double* __restrict__ partial) {
    double cnt = 0.0, sx[C], s2[C];
#pragma unroll
    for (int c = 0; c < C; c++) { sx[c] = 0.0; s2[c] = 0.0; }
    int stride = gridDim.x * blockDim.x;
    for (int v = blockIdx.x * blockDim.x + threadIdx.x; v < N; v += stride) {
        if (!m[v]) continue;
        cnt += 1.0;
#pragma unroll
        for (int c = 0; c < C; c++) {
            double xv = (double)x[(size_t)v * C + c];
            sx[c] += xv;
            s2[c] += xv * xv;
        }
    }
#pragma unroll
    for (int off = 32; off > 0; off >>= 1) {
        cnt += __shfl_down(cnt, off, 64);
#pragma unroll
        for (int c = 0; c < C; c++) {
            sx[c] += __shfl_down(sx[c], off, 64);
            s2[c] += __shfl_down(s2[c], off, 64);
        }
    }
    __shared__ double sbuf[4][2 * C + 1];
    int wave = threadIdx.x >> 6;
    if ((threadIdx.x & 63) == 0) {
        sbuf[wave][0] = cnt;
#pragma unroll
        for (int c = 0; c < C; c++) {
            sbuf[wave][1 + c] = sx[c];
            sbuf[wave][1 + C + c] = s2[c];
        }
    }
    __syncthreads();
    if (threadIdx.x == 0) {
        double* p = partial + (size_t)blockIdx.x * (2 * C + 1);
        double tcnt = 0.0;
        for (int wv = 0; wv < 4; wv++) tcnt += sbuf[wv][0];
        p[0] = tcnt;
#pragma unroll
        for (int c = 0; c < C; c++) {
            double a = 0.0, b = 0.0;
            for (int wv = 0; wv < 4; wv++) { a += sbuf[wv][1 + c]; b += sbuf[wv][1 + C + c]; }
            p[1 + c] = a;
            p[1 + C + c] = b;
        }
    }
}

// ---------------- BN finalize: fixed-order sum of block partials ----------------
template <int C>
__global__ void bn_final_k(const double* __restrict__ partial, int nblocks,
                           const float* __restrict__ g, const float* __restrict__ b,
                           double* __restrict__ params) {
    int c = threadIdx.x;
    if (c >= C) return;
    double cnt = 0.0, sx = 0.0, s2 = 0.0;
    for (int bk = 0; bk < nblocks; bk++) {
        const double* p = partial + (size_t)bk * (2 * C + 1);
        cnt += p[0];
        sx += p[1 + c];
        s2 += p[1 + C + c];
    }
    if (cnt < 1.0) cnt = 1.0;
    double mean = sx / cnt;
    double var = s2 / cnt - mean * mean;
    double sc = (double)g[c] / sqrt(var + 1e-4);
    params[c] = sc;
    params[C + c] = (double)b[c] - mean * sc;
}

// ---------------- hidden: NDHWC (4^3, 32ch) -> NCDHW flat ----------------
__global__ void hidden_k(const float* __restrict__ x, float* __restrict__ out) {
    int i = blockIdx.x * blockDim.x + threadIdx.x;
    if (i >= 128 * 2048) return;
    int b = i >> 11;
    int r = i & 2047;
    int c = r >> 6;
    int s = r & 63;
    int d = s >> 4;
    int h = (s >> 2) & 3;
    int w = s & 3;
    out[i] = x[((((b * 4 + d) * 4 + h) * 4 + w) << 5) + c];
}

extern "C" void kernel_launch(void* const* d_in, const int* in_sizes, int n_in,
                              void* d_out, int out_size, void* d_ws, size_t ws_size,
                              hipStream_t stream) {
    const float* vox = (const float*)d_in[0];
    const int* mraw = (const int*)d_in[1];
    const float* wp = (const float*)d_in[2];
    const float* g_e0 = (const float*)d_in[3];
    const float* b_e0 = (const float*)d_in[4];
    const float* ws_e0 = (const float*)d_in[5];
    const float* wd_e0 = (const float*)d_in[6];
    const float* g_e1 = (const float*)d_in[7];
    const float* b_e1 = (const float*)d_in[8];
    const float* ws_e1 = (const float*)d_in[9];
    const float* wd_e1 = (const float*)d_in[10];
    const float* g_e2 = (const float*)d_in[11];
    const float* b_e2 = (const float*)d_in[12];
    const float* ws_e2 = (const float*)d_in[13];
    const float* wd_e2 = (const float*)d_in[14];
    const float* g_d0 = (const float*)d_in[15];
    const float* b_d0 = (const float*)d_in[16];
    const float* wu_d0 = (const float*)d_in[17];
    const float* ws3_d0 = (const float*)d_in[18];
    const float* ws4_d0 = (const float*)d_in[19];
    const float* g_d1 = (const float*)d_in[20];
    const float* b_d1 = (const float*)d_in[21];
    const float* wu_d1 = (const float*)d_in[22];
    const float* ws3_d1 = (const float*)d_in[23];
    const float* ws4_d1 = (const float*)d_in[24];
    const float* g_d2 = (const float*)d_in[25];
    const float* b_d2 = (const float*)d_in[26];
    const float* wu_d2 = (const float*)d_in[27];
    const float* ws3_d2 = (const float*)d_in[28];
    const float* ws4_d2 = (const float*)d_in[29];
    const float* wo = (const float*)d_in[30];
    float* out = (float*)d_out;

    // ---- workspace: fp32 tensors + fp64 partials/params + u8 masks (~153 MB) ----
    float* wsf = (float*)d_ws;
    size_t offf = 0;
    auto allocf = [&](size_t n) { float* p = wsf + offf; offf += n; return p; };
    float* R1 = allocf(16777216);
    float* R2 = allocf(16777216);
    float* S1 = allocf(1048576);
    float* S2 = allocf(1048576);
    float* T = allocf(262144);
    double* wsd = (double*)(wsf + offf);
    double* partial = wsd;          // up to 256 blocks x (2*32+1) doubles
    double* params = wsd + 16640;
    u8* wsm = (u8*)(wsd + 16640 + 128);
    size_t offm = 0;
    auto allocm = [&](size_t n) { u8* p = wsm + offm; offm += n; return p; };
    u8* m32 = allocm(4194304);
    u8* m16 = allocm(524288);
    u8* m8 = allocm(65536);
    u8* m4 = allocm(8192);
    u8* mD8 = allocm(65536);
    u8* mD16 = allocm(524288);
    u8* mD32 = allocm(4194304);

    const int N32 = 128 * 32768;
    const int N16 = 128 * 4096;
    const int N8 = 128 * 512;
    const int N4 = 128 * 64;
    const int NG32 = N32 / 4;
    auto gs = [](int n) { return dim3((n + 255) / 256); };
    auto rbn = [](int n) { int bl = (n + 255) / 256; return bl > 256 ? 256 : bl; };
    dim3 blk(256);

    // masks
    mask_init_k<<<gs(N32), blk, 0, stream>>>(mraw, m32, N32);
    pool_k<16><<<gs(N16), blk, 0, stream>>>(m32, m16);
    pool_k<8><<<gs(N8), blk, 0, stream>>>(m16, m8);
    pool_k<4><<<gs(N4), blk, 0, stream>>>(m8, m4);

    // ---- encoder stage 0 @32^3, full batch ----
    prep4_k<<<gs(NG32), blk, 0, stream>>>(vox, m32, wp, R1);
    int nb0 = rbn(N32);
    bn_reduce_k<4><<<dim3(nb0), blk, 0, stream>>>(R1, m32, N32, partial);
    bn_final_k<4><<<1, 64, 0, stream>>>(partial, nb0, g_e0, b_e0, params);
    convbn4_k<<<gs(NG32), blk, 0, stream>>>(R1, ws_e0, m32, params, R2);
    down_k<4, 8, 16><<<gs(N16), blk, 0, stream>>>(R2, wd_e0, m16, R1);

    // ---- encoder stage 1 @16^3 ----
    int nb1 = rbn(N16);
    bn_reduce_k<8><<<dim3(nb1), blk, 0, stream>>>(R1, m16, N16, partial);
    bn_final_k<8><<<1, 64, 0, stream>>>(partial, nb1, g_e1, b_e1, params);
    convbn_k<8, 8, 16><<<gs(N16), blk, 0, stream>>>(R1, ws_e1, m16, params, R2);
    down_k<8, 16, 8><<<gs(N8), blk, 0, stream>>>(R2, wd_e1, m8, S1);

    // ---- encoder stage 2 @8^3 ----
    int nb2 = rbn(N8);
    bn_reduce_k<16><<<dim3(nb2), blk, 0, stream>>>(S1, m8, N8, partial);
    bn_final_k<16><<<1, 64, 0, stream>>>(partial, nb2, g_e2, b_e2, params);
    convbn_k<16, 16, 8><<<gs(N8), blk, 0, stream>>>(S1, ws_e2, m8, params, S2);
    down_k<16, 32, 4><<<gs(N4), blk, 0, stream>>>(S2, wd_e2, m4, T);

    // ---- hidden ----
    hidden_k<<<gs(128 * 2048), blk, 0, stream>>>(T, out);

    // ---- decoder stage 0 (32->16, 4^3 -> 8^3), band gate delta=4e-7 ----
    int nb3 = rbn(N4);
    bn_reduce_k<32><<<dim3(nb3), blk, 0, stream>>>(T, m4, N4, partial);
    bn_final_k<32><<<1, 64, 0, stream>>>(partial, nb3, g_d0, b_d0, params);
    upbn_k<32, 16, 4><<<gs(N8), blk, 0, stream>>>(T, wu_d0, m4, params, S1);
    conv3s_k<16, 16, 8><<<gs(N8), blk, 0, stream>>>(S1, ws3_d0, m4, mD8, S2, 4e-7);
    conv_k<4, 16, 16, 8><<<gs(N8), blk, 0, stream>>>(S2, ws4_d0, mD8, S1);

    // ---- decoder stage 1 (16->8, 8^3 -> 16^3), band gate delta=4e-7 ----
    int nb4 = rbn(N8);
    bn_reduce_k<16><<<dim3(nb4), blk, 0, stream>>>(S1, mD8, N8, partial);
    bn_final_k<16><<<1, 64, 0, stream>>>(partial, nb4, g_d1, b_d1, params);
    upbn_k<16, 8, 8><<<gs(N16), blk, 0, stream>>>(S1, wu_d1, mD8, params, R1);
    conv3s_k<8, 8, 16><<<gs(N16), blk, 0, stream>>>(R1, ws3_d1, mD8, mD16, R2, 4e-7);
    conv_k<4, 8, 8, 16><<<gs(N16), blk, 0, stream>>>(R2, ws4_d1, mD16, R1);

    // ---- decoder stage 2 (8->4, 16^3 -> 32^3), exact gate ----
    int nb5 = rbn(N16);
    bn_reduce_k<8><<<dim3(nb5), blk, 0, stream>>>(R1, mD16, N16, partial);
    bn_final_k<8><<<1, 64, 0, stream>>>(partial, nb5, g_d2, b_d2, params);
    upbn_k<8, 4, 16><<<gs(N32), blk, 0, stream>>>(R1, wu_d2, mD16, params, R2);
    conv3s4_k<<<gs(NG32), blk, 0, stream>>>(R2, ws3_d2, mD16, mD32, R1, 0.0);
    conv4x4_k<4><<<gs(NG32), blk, 0, stream>>>(R1, ws4_d2, mD32, R2);
    outconv4_k<<<gs(NG32), blk, 0, stream>>>(R2, wo, mD32, out + 262144);
}